// Round 5
// baseline (841.462 us; speedup 1.0000x reference)
//
#include <hip/hip_runtime.h>
#include <hip/hip_bf16.h>

namespace {
constexpr int kB = 4;
constexpr int kC = 512;
constexpr int kH = 128;
constexpr int kW = 128;
constexpr int kCQK = 64;
constexpr int kL = kH * kW;   // 16384
constexpr int kO = 640;       // rows: [0,64)=Wq, [64,128)=Wk, [128,640)=Wv

// workspace layout (float offsets)
constexpr size_t OFF_WALL = 0;                          // wpk: 640*512*2 bf16
constexpr size_t OFF_BALL = (size_t)kO * kC;            // 640
constexpr size_t OFF_QKV  = OFF_BALL + kO;              // B*640*L fp32
constexpr size_t OFF_E    = OFF_QKV + (size_t)kB * kO * kL;  // B*H*W*256 fp32
constexpr size_t WS_FLOATS = OFF_E + (size_t)kB * kH * kW * 256;
// NOTE: after ecol, the q/k rows of qkv (first 128 rows per batch = 8.4MB/b) are dead.
// softmax reuses that region per-batch as acolT[b][w][h][j] bf16 (4.2MB/b).

typedef __attribute__((ext_vector_type(8))) short bf16x8;
typedef __attribute__((ext_vector_type(4))) float f32x4;

__device__ __forceinline__ unsigned short f32_to_bf16_rn(float f) {
  unsigned u = __float_as_uint(f);
  unsigned r = (u + 0x7FFFu + ((u >> 16) & 1u)) >> 16;
  return (unsigned short)r;
}
__device__ __forceinline__ float bf16_to_f32(unsigned short h) {
  return __uint_as_float(((unsigned)h) << 16);
}
__device__ __forceinline__ unsigned pack_bf16x2(float a, float b) {
  return (unsigned)f32_to_bf16_rn(a) | ((unsigned)f32_to_bf16_rn(b) << 16);
}
}

// ---------------- pack W/bias into bf16 hi/lo planes [640][512] ----------------
__global__ __launch_bounds__(256) void pack_w(
    const float* __restrict__ Wq, const float* __restrict__ bq,
    const float* __restrict__ Wk, const float* __restrict__ bk,
    const float* __restrict__ Wv, const float* __restrict__ bv,
    short* __restrict__ wpk, float* __restrict__ ball) {
  const int r = blockIdx.x;      // 0..639
  const int t = threadIdx.x;     // 256
  const float* src;
  if (r < 64) {
    src = Wq + (size_t)r * kC;
    if (t == 0) ball[r] = bq[r];
  } else if (r < 128) {
    src = Wk + (size_t)(r - 64) * kC;
    if (t == 0) ball[r] = bk[r - 64];
  } else {
    src = Wv + (size_t)(r - 128) * kC;
    if (t == 0) ball[r] = bv[r - 128];
  }
#pragma unroll
  for (int p = 0; p < 2; ++p) {
    const int c = p * 256 + t;
    const float v = src[c];
    const unsigned short h = f32_to_bf16_rn(v);
    const unsigned short l = f32_to_bf16_rn(v - bf16_to_f32(h));
    wpk[(size_t)r * kC + c] = (short)h;
    wpk[(size_t)kO * kC + (size_t)r * kC + c] = (short)l;
  }
}

// ---------------- pack x (one batch): fp32 [c][l] -> bf16 hi/lo [l][c] ----------------
__global__ __launch_bounds__(256) void pack_x(
    const float* __restrict__ x, short* __restrict__ xpk, int b) {
  __shared__ float sT[64][65];
  const int l0 = blockIdx.x * 64;
  const int c0 = blockIdx.y * 64;
  const int t = threadIdx.x;
  const float* xb = x + (size_t)b * kC * kL;
#pragma unroll
  for (int p = 0; p < 4; ++p) {
    const int ch = p * 256 + t;
    const int c = ch >> 4, l4 = (ch & 15) * 4;
    float4 v = *(const float4*)(xb + (size_t)(c0 + c) * kL + l0 + l4);
    sT[c][l4 + 0] = v.x; sT[c][l4 + 1] = v.y; sT[c][l4 + 2] = v.z; sT[c][l4 + 3] = v.w;
  }
  __syncthreads();
#pragma unroll
  for (int p = 0; p < 2; ++p) {
    const int ch = p * 256 + t;
    const int l = ch >> 3, cg = ch & 7;
    short hi[8], lo[8];
#pragma unroll
    for (int j = 0; j < 8; ++j) {
      const float v = sT[cg * 8 + j][l];
      const unsigned short h = f32_to_bf16_rn(v);
      hi[j] = (short)h;
      lo[j] = (short)f32_to_bf16_rn(v - bf16_to_f32(h));
    }
    short* dh = xpk + (size_t)(l0 + l) * kC + c0 + cg * 8;
    *(bf16x8*)dh = *(bf16x8*)hi;
    *(bf16x8*)(dh + (size_t)kL * kC) = *(bf16x8*)lo;
  }
}

// ---------------- projection GEMM via bf16 MFMA, split precision ----------------
__global__ __launch_bounds__(256, 2) void proj_mfma(
    const short* __restrict__ xpk, const short* __restrict__ wpk,
    const float* __restrict__ ball, float* __restrict__ qkv, int b) {
  __shared__ short A_h[128 * 64];
  __shared__ short A_l[128 * 64];
  __shared__ short B_h[128 * 64];
  __shared__ short B_l[128 * 64];
  const int mt = blockIdx.x;          // 0..4
  const int n0 = blockIdx.y * 128;
  const int m0 = mt * 128;
  const bool qk = (mt == 0);
  const int t = threadIdx.x;
  const int wid = t >> 6, lane = t & 63;
  const int wr = wid >> 1, wc = wid & 1;
  const int lr = lane & 15, lg = lane >> 4;

  f32x4 acc[4][4];
#pragma unroll
  for (int i = 0; i < 4; ++i)
#pragma unroll
    for (int j = 0; j < 4; ++j) acc[i][j] = (f32x4)(0.f);

  for (int kt = 0; kt < 8; ++kt) {
    const int k0 = kt * 64;
#pragma unroll
    for (int p = 0; p < 4; ++p) {
      const int ch = p * 256 + t;
      const int row = ch >> 3, kg = ch & 7;
      const short* src = wpk + (size_t)(m0 + row) * kC + k0 + kg * 8;
      const int off = row * 64 + ((kg ^ (row & 7)) << 3);
      *(bf16x8*)&A_h[off] = *(const bf16x8*)src;
      *(bf16x8*)&A_l[off] = *(const bf16x8*)(src + (size_t)kO * kC);
    }
#pragma unroll
    for (int p = 0; p < 4; ++p) {
      const int ch = p * 256 + t;
      const int row = ch >> 3, kg = ch & 7;
      const short* src = xpk + (size_t)(n0 + row) * kC + k0 + kg * 8;
      const int off = row * 64 + ((kg ^ (row & 7)) << 3);
      *(bf16x8*)&B_h[off] = *(const bf16x8*)src;
      if (qk) *(bf16x8*)&B_l[off] = *(const bf16x8*)(src + (size_t)kL * kC);
    }
    __syncthreads();
#pragma unroll
    for (int ks = 0; ks < 2; ++ks) {
      bf16x8 ah[4], al[4], bh[4], bl[4];
#pragma unroll
      for (int mf = 0; mf < 4; ++mf) {
        const int row = wr * 64 + mf * 16 + lr;
        const int kg = ks * 4 + lg;
        const int off = row * 64 + ((kg ^ (row & 7)) << 3);
        ah[mf] = *(const bf16x8*)&A_h[off];
        al[mf] = *(const bf16x8*)&A_l[off];
      }
#pragma unroll
      for (int nf = 0; nf < 4; ++nf) {
        const int row = wc * 64 + nf * 16 + lr;
        const int kg = ks * 4 + lg;
        const int off = row * 64 + ((kg ^ (row & 7)) << 3);
        bh[nf] = *(const bf16x8*)&B_h[off];
        if (qk) bl[nf] = *(const bf16x8*)&B_l[off];
      }
#pragma unroll
      for (int mf = 0; mf < 4; ++mf)
#pragma unroll
        for (int nf = 0; nf < 4; ++nf) {
          acc[mf][nf] = __builtin_amdgcn_mfma_f32_16x16x32_bf16(
              ah[mf], bh[nf], acc[mf][nf], 0, 0, 0);
          acc[mf][nf] = __builtin_amdgcn_mfma_f32_16x16x32_bf16(
              al[mf], bh[nf], acc[mf][nf], 0, 0, 0);
          if (qk)
            acc[mf][nf] = __builtin_amdgcn_mfma_f32_16x16x32_bf16(
                ah[mf], bl[nf], acc[mf][nf], 0, 0, 0);
        }
    }
    __syncthreads();
  }
#pragma unroll
  for (int mf = 0; mf < 4; ++mf) {
#pragma unroll
    for (int r = 0; r < 4; ++r) {
      const int m = m0 + wr * 64 + mf * 16 + lg * 4 + r;
      const float bias = ball[m];
      float* dst = qkv + ((size_t)b * kO + m) * kL + n0 + wc * 64;
#pragma unroll
      for (int nf = 0; nf < 4; ++nf) {
        dst[nf * 16 + lr] = acc[mf][nf][r] + bias;
      }
    }
  }
}

// ---------------- e_row ----------------
__global__ __launch_bounds__(256) void erow_kernel(
    const float* __restrict__ qkv, float* __restrict__ e) {
  __shared__ float sQ[32][128];
  __shared__ float sK[32][128];
  const int bh = blockIdx.x;
  const int b = bh >> 7, h = bh & 127;
  const int t = threadIdx.x;
  const int tx = t & 15, ty = t >> 4;
  float acc[8][8];
#pragma unroll
  for (int i = 0; i < 8; ++i)
#pragma unroll
    for (int j = 0; j < 8; ++j) acc[i][j] = 0.f;

  for (int k0 = 0; k0 < kCQK; k0 += 32) {
#pragma unroll
    for (int p = 0; p < 4; ++p) {
      const int idx = p * 256 + t;
      const int cc = idx >> 5, w4 = (idx & 31) * 4;
      const size_t base = ((size_t)b * kO + k0 + cc) * kL + h * kW + w4;
      *(float4*)&sQ[cc][w4] = *(const float4*)(qkv + base);
      *(float4*)&sK[cc][w4] = *(const float4*)(qkv + base + (size_t)64 * kL);
    }
    __syncthreads();
#pragma unroll
    for (int kk = 0; kk < 32; ++kk) {
      float a[8], bb[8];
      *(float4*)(a + 0) = *(const float4*)&sQ[kk][ty * 8];
      *(float4*)(a + 4) = *(const float4*)&sQ[kk][ty * 8 + 4];
      *(float4*)(bb + 0) = *(const float4*)&sK[kk][tx * 8];
      *(float4*)(bb + 4) = *(const float4*)&sK[kk][tx * 8 + 4];
#pragma unroll
      for (int wi = 0; wi < 8; ++wi)
#pragma unroll
        for (int ii = 0; ii < 8; ++ii) acc[wi][ii] = fmaf(a[wi], bb[ii], acc[wi][ii]);
    }
    __syncthreads();
  }
#pragma unroll
  for (int wi = 0; wi < 8; ++wi) {
    const int w = ty * 8 + wi;
    float* dst = e + (((size_t)b * kH + h) * kW + w) * 256 + tx * 8;
    float4 o0 = {acc[wi][0], acc[wi][1], acc[wi][2], acc[wi][3]};
    float4 o1 = {acc[wi][4], acc[wi][5], acc[wi][6], acc[wi][7]};
    *(float4*)(dst + 0) = o0;
    *(float4*)(dst + 4) = o1;
  }
}

// ---------------- e_col ----------------
__global__ __launch_bounds__(256) void ecol_kernel(
    const float* __restrict__ qkv, float* __restrict__ e) {
  __shared__ float sQ[32][128];
  __shared__ float sK[32][128];
  const int bw = blockIdx.x;
  const int b = bw >> 7, w = bw & 127;
  const int t = threadIdx.x;
  const int tx = t & 15, ty = t >> 4;
  float acc[8][8];
#pragma unroll
  for (int i = 0; i < 8; ++i)
#pragma unroll
    for (int j = 0; j < 8; ++j) acc[i][j] = 0.f;

  for (int k0 = 0; k0 < kCQK; k0 += 32) {
#pragma unroll
    for (int p = 0; p < 16; ++p) {
      const int idx = p * 256 + t;
      const int cc = idx >> 7, hh = idx & 127;
      const size_t base = ((size_t)b * kO + k0 + cc) * kL + hh * kW + w;
      sQ[cc][hh] = qkv[base];
      sK[cc][hh] = qkv[base + (size_t)64 * kL];
    }
    __syncthreads();
#pragma unroll
    for (int kk = 0; kk < 32; ++kk) {
      float a[8], bb[8];
      *(float4*)(a + 0) = *(const float4*)&sQ[kk][ty * 8];
      *(float4*)(a + 4) = *(const float4*)&sQ[kk][ty * 8 + 4];
      *(float4*)(bb + 0) = *(const float4*)&sK[kk][tx * 8];
      *(float4*)(bb + 4) = *(const float4*)&sK[kk][tx * 8 + 4];
#pragma unroll
      for (int hi = 0; hi < 8; ++hi)
#pragma unroll
        for (int ji = 0; ji < 8; ++ji) acc[hi][ji] = fmaf(a[hi], bb[ji], acc[hi][ji]);
    }
    __syncthreads();
  }
  const float NEG_INF = __int_as_float(0xff800000);
#pragma unroll
  for (int hi = 0; hi < 8; ++hi) {
    const int h = ty * 8 + hi;
    float vals[8];
#pragma unroll
    for (int ji = 0; ji < 8; ++ji) {
      const int j = tx * 8 + ji;
      vals[ji] = (j == h) ? NEG_INF : acc[hi][ji];
    }
    float* dst = e + (((size_t)b * kH + h) * kW + w) * 256 + 128 + tx * 8;
    float4 o0 = {vals[0], vals[1], vals[2], vals[3]};
    float4 o1 = {vals[4], vals[5], vals[6], vals[7]};
    *(float4*)(dst + 0) = o0;
    *(float4*)(dst + 4) = o1;
  }
}

// ---------------- softmax; row half -> fp32 in place, col half -> bf16 acolT ----
// acolT[b][w][h][j] lives in the dead q/k region of qkv (per-batch).
__global__ __launch_bounds__(256) void softmax_kernel(
    float* __restrict__ e, float* qkv_base) {
  const int t = threadIdx.x;
  const int wv = t >> 6, lane = t & 63;
  const size_t pix = (size_t)blockIdx.x * 4 + wv;
  float* p = e + pix * 256 + lane * 4;
  float4 v = *(const float4*)p;
  float m = fmaxf(fmaxf(v.x, v.y), fmaxf(v.z, v.w));
#pragma unroll
  for (int off = 32; off > 0; off >>= 1) m = fmaxf(m, __shfl_xor(m, off, 64));
  float e0 = expf(v.x - m), e1 = expf(v.y - m), e2 = expf(v.z - m), e3 = expf(v.w - m);
  float s = e0 + e1 + e2 + e3;
#pragma unroll
  for (int off = 32; off > 0; off >>= 1) s += __shfl_xor(s, off, 64);
  const float inv = 1.0f / s;
  const float o0 = e0 * inv, o1 = e1 * inv, o2 = e2 * inv, o3 = e3 * inv;
  if (lane < 32) {
    float4 o = {o0, o1, o2, o3};
    *(float4*)p = o;                           // a_row stays fp32
  } else {
    const int b = (int)(pix >> 14);
    const int h = (int)((pix >> 7) & 127);
    const int w = (int)(pix & 127);
    const int j = (lane - 32) * 4;
    unsigned lo = pack_bf16x2(o0, o1);
    unsigned hi = pack_bf16x2(o2, o3);
    unsigned short* dst = (unsigned short*)qkv_base + (size_t)b * kO * kL * 2
        + ((size_t)w * kH + h) * 128 + j;
    *(uint2*)dst = make_uint2(lo, hi);
  }
}

// ---------------- row aggregation (fp32) ----------------
__global__ __launch_bounds__(256) void rowagg_kernel(
    const float* __restrict__ qkv, const float* __restrict__ e,
    float* __restrict__ out) {
  __shared__ float sV[32][132];
  __shared__ float sA[32][132];
  const int bh = blockIdx.y;
  const int b = bh >> 7, h = bh & 127;
  const int m0 = blockIdx.x * 128;
  const int t = threadIdx.x;
  const int tx = t & 15, ty = t >> 4;
  float acc[8][8];
#pragma unroll
  for (int i = 0; i < 8; ++i)
#pragma unroll
    for (int j = 0; j < 8; ++j) acc[i][j] = 0.f;

  for (int i0 = 0; i0 < kW; i0 += 32) {
    {
      const int c = t >> 1, ih = (t & 1) * 16;
      const float* src =
          qkv + ((size_t)b * kO + 128 + m0 + c) * kL + h * kW + i0 + ih;
      float tmp[16];
      *(float4*)(tmp + 0)  = *(const float4*)(src + 0);
      *(float4*)(tmp + 4)  = *(const float4*)(src + 4);
      *(float4*)(tmp + 8)  = *(const float4*)(src + 8);
      *(float4*)(tmp + 12) = *(const float4*)(src + 12);
#pragma unroll
      for (int r = 0; r < 16; ++r) sV[ih + r][c] = tmp[r];
    }
#pragma unroll
    for (int p = 0; p < 4; ++p) {
      const int idx = p * 256 + t;
      const int ww = idx >> 3, q = idx & 7;
      float4 av = *(const float4*)(
          e + (((size_t)b * kH + h) * kW + ww) * 256 + i0 + q * 4);
      sA[q * 4 + 0][ww] = av.x;
      sA[q * 4 + 1][ww] = av.y;
      sA[q * 4 + 2][ww] = av.z;
      sA[q * 4 + 3][ww] = av.w;
    }
    __syncthreads();
#pragma unroll
    for (int kk = 0; kk < 32; ++kk) {
      float a[8], bb[8];
      *(float4*)(a + 0) = *(const float4*)&sV[kk][ty * 8];
      *(float4*)(a + 4) = *(const float4*)&sV[kk][ty * 8 + 4];
      *(float4*)(bb + 0) = *(const float4*)&sA[kk][tx * 8];
      *(float4*)(bb + 4) = *(const float4*)&sA[kk][tx * 8 + 4];
#pragma unroll
      for (int ci = 0; ci < 8; ++ci)
#pragma unroll
        for (int wi = 0; wi < 8; ++wi) acc[ci][wi] = fmaf(a[ci], bb[wi], acc[ci][wi]);
    }
    __syncthreads();
  }
#pragma unroll
  for (int ci = 0; ci < 8; ++ci) {
    const int c = m0 + ty * 8 + ci;
    float* dst = out + (((size_t)b * kC + c) * kH + h) * kW + tx * 8;
    float4 o0 = {acc[ci][0], acc[ci][1], acc[ci][2], acc[ci][3]};
    float4 o1 = {acc[ci][4], acc[ci][5], acc[ci][6], acc[ci][7]};
    *(float4*)(dst + 0) = o0;
    *(float4*)(dst + 4) = o1;
  }
}

// ---------------- col aggregation via bf16 MFMA (v3: latency-hiding) ----------------
// out[b][c][h][w] += sum_j acolT[b][w][h][j] * v[b][c][j][w]
// Block: (b, c-tile 64, h-tile 64, w-tile 4); 4 waves, wave wv owns w = w0+wv.
// V register-prefetched across K-steps then packed to LDS (2-way swizzle);
// A frags read DIRECT from global acolT (full 64B lines, L2-shared across ct).
__global__ __launch_bounds__(256) void colagg_mfma(
    const float* qkv, float* __restrict__ out) {
  __shared__ unsigned sV[4 * 64 * 16];   // [w][c][jp phys] b32 = (j even, j odd)
  const int gx = blockIdx.x;             // ct(8) + 8*ht(2); c innermost for A L2 reuse
  const int ct = gx & 7, ht = gx >> 3;
  const int c0 = ct * 64, h0 = ht * 64;
  const int w0 = blockIdx.y * 4;
  const int b = blockIdx.z;
  const int t = threadIdx.x;
  const int wv = t >> 6, lane = t & 63;
  const int lr = lane & 15, lg = lane >> 4;
  const int w = w0 + wv;

  f32x4 acc[4][4];   // [mf(c)][nf(h)]
#pragma unroll
  for (int i = 0; i < 4; ++i)
#pragma unroll
    for (int j = 0; j < 4; ++j) acc[i][j] = (f32x4)(0.f);

  const float* vbase = qkv + ((size_t)b * kO + 128 + c0) * kL + w0;
  const unsigned short* ab = (const unsigned short*)qkv
      + (size_t)b * kO * kL * 2 + (size_t)w * (kH * 128);

  // V staging roles: this thread covers c = vc + 16*i, j-pair vjp
  const int vc = (lane >> 4) + 4 * wv;   // 0..15
  const int vjp = lane & 15;
  const int vq = vjp >> 2, vr = vjp & 3;

  // prefetch K-step 0
  float4 pv0[4], pv1[4];
#pragma unroll
  for (int i = 0; i < 4; ++i) {
    const float* src = vbase + (size_t)(vc + 16 * i) * kL + (size_t)(2 * vjp) * kW;
    pv0[i] = *(const float4*)src;
    pv1[i] = *(const float4*)(src + kW);
  }

  for (int kt = 0; kt < 4; ++kt) {
    const int j0 = kt * 32;
    // ---- pack current prefetch into LDS ----
#pragma unroll
    for (int i = 0; i < 4; ++i) {
      const int c = vc + 16 * i;
      const int s = (c & 3) ^ ((c >> 2) & 3);
      const int idx = c * 16 + ((vq ^ s) << 2) + vr;
      sV[0 * 1024 + idx] = pack_bf16x2(pv0[i].x, pv1[i].x);
      sV[1 * 1024 + idx] = pack_bf16x2(pv0[i].y, pv1[i].y);
      sV[2 * 1024 + idx] = pack_bf16x2(pv0[i].z, pv1[i].z);
      sV[3 * 1024 + idx] = pack_bf16x2(pv0[i].w, pv1[i].w);
    }
    // ---- issue next K-step's V gathers (hidden under MFMA) ----
    if (kt < 3) {
#pragma unroll
      for (int i = 0; i < 4; ++i) {
        const float* src =
            vbase + (size_t)(vc + 16 * i) * kL + (size_t)(j0 + 32 + 2 * vjp) * kW;
        pv0[i] = *(const float4*)src;
        pv1[i] = *(const float4*)(src + kW);
      }
    }
    // ---- A frags direct from global (coalesced full lines) ----
    bf16x8 af[4];
#pragma unroll
    for (int nf = 0; nf < 4; ++nf) {
      const int h = h0 + nf * 16 + lr;
      af[nf] = *(const bf16x8*)(ab + (size_t)h * 128 + j0 + lg * 8);
    }
    __syncthreads();
    bf16x8 vf[4];
#pragma unroll
    for (int mf = 0; mf < 4; ++mf) {
      const int c = mf * 16 + lr;
      const int s = (c & 3) ^ ((c >> 2) & 3);
      vf[mf] = *(const bf16x8*)&sV[wv * 1024 + c * 16 + ((lg ^ s) << 2)];
    }
#pragma unroll
    for (int mf = 0; mf < 4; ++mf)
#pragma unroll
      for (int nf = 0; nf < 4; ++nf)
        acc[mf][nf] = __builtin_amdgcn_mfma_f32_16x16x32_bf16(
            vf[mf], af[nf], acc[mf][nf], 0, 0, 0);
    __syncthreads();
  }
  // ---- epilogue: scalar RMW (D: row=c=4lg+r, col=h=lr) ----
#pragma unroll
  for (int mf = 0; mf < 4; ++mf) {
#pragma unroll
    for (int r = 0; r < 4; ++r) {
      const int c = c0 + mf * 16 + lg * 4 + r;
      float* dst = out + (((size_t)b * kC + c) * kH + h0) * kW + w;
#pragma unroll
      for (int nf = 0; nf < 4; ++nf) {
        dst[(nf * 16 + lr) * kW] += acc[mf][nf][r];
      }
    }
  }
}

extern "C" void kernel_launch(void* const* d_in, const int* in_sizes, int n_in,
                              void* d_out, int out_size, void* d_ws, size_t ws_size,
                              hipStream_t stream) {
  (void)in_sizes; (void)n_in; (void)out_size; (void)ws_size;
  const float* x  = (const float*)d_in[0];
  const float* Wq = (const float*)d_in[1];
  const float* bq = (const float*)d_in[2];
  const float* Wk = (const float*)d_in[3];
  const float* bk = (const float*)d_in[4];
  const float* Wv = (const float*)d_in[5];
  const float* bv = (const float*)d_in[6];
  float* out = (float*)d_out;
  float* ws  = (float*)d_ws;

  short* wpk = (short*)(ws + OFF_WALL);
  float* ball = ws + OFF_BALL;
  float* qkv  = ws + OFF_QKV;
  float* e    = ws + OFF_E;
  short* xpk  = (short*)(ws + OFF_E);   // aliases e (used only before e is written)

  pack_w<<<dim3(kO), dim3(256), 0, stream>>>(Wq, bq, Wk, bk, Wv, bv, wpk, ball);
  for (int b = 0; b < kB; ++b) {
    pack_x<<<dim3(kL / 64, kC / 64), dim3(256), 0, stream>>>(x, xpk, b);
    proj_mfma<<<dim3(5, kL / 128), dim3(256), 0, stream>>>(xpk, wpk, ball, qkv, b);
  }
  erow_kernel<<<dim3(kB * kH), dim3(256), 0, stream>>>(qkv, e);
  ecol_kernel<<<dim3(kB * kW), dim3(256), 0, stream>>>(qkv, e);
  softmax_kernel<<<dim3(kB * kH * kW / 4), dim3(256), 0, stream>>>(e, qkv);
  rowagg_kernel<<<dim3(kC / 128, kB * kH), dim3(256), 0, stream>>>(qkv, e, out);
  colagg_mfma<<<dim3(16, kW / 4, kB), dim3(256), 0, stream>>>(qkv, out);
}

// Round 6
// 651.283 us; speedup vs baseline: 1.2920x; 1.2920x over previous
//
#include <hip/hip_runtime.h>
#include <hip/hip_bf16.h>

namespace {
constexpr int kB = 4;
constexpr int kC = 512;
constexpr int kH = 128;
constexpr int kW = 128;
constexpr int kCQK = 64;
constexpr int kL = kH * kW;   // 16384
constexpr int kO = 640;       // rows: [0,64)=Wq, [64,128)=Wk, [128,640)=Wv

// workspace layout (float offsets)
constexpr size_t OFF_WALL = 0;                          // wpk: 640*512*2 bf16
constexpr size_t OFF_BALL = (size_t)kO * kC;            // 640
constexpr size_t OFF_QKV  = OFF_BALL + kO;              // B*640*L fp32
constexpr size_t OFF_E    = OFF_QKV + (size_t)kB * kO * kL;  // B*H*W*256 fp32
constexpr size_t WS_FLOATS = OFF_E + (size_t)kB * kH * kW * 256;
// After ecol, the q/k rows of qkv (first 128 rows/batch = 8.4MB/b) are dead.
// softmax reuses them as afrag[b][w][jb 4][hb 8][lane 64][8] bf16 (4MB/b).

typedef __attribute__((ext_vector_type(8))) short bf16x8;
typedef __attribute__((ext_vector_type(4))) float f32x4;

__device__ __forceinline__ unsigned short f32_to_bf16_rn(float f) {
  unsigned u = __float_as_uint(f);
  unsigned r = (u + 0x7FFFu + ((u >> 16) & 1u)) >> 16;
  return (unsigned short)r;
}
__device__ __forceinline__ float bf16_to_f32(unsigned short h) {
  return __uint_as_float(((unsigned)h) << 16);
}
__device__ __forceinline__ unsigned pack_bf16x2(float a, float b) {
  return (unsigned)f32_to_bf16_rn(a) | ((unsigned)f32_to_bf16_rn(b) << 16);
}
// sV layout strides (u32 units): [c][w][jq][jr], jr contig(4), Sw=20, Sc=324
constexpr int SVW = 20;
constexpr int SVC = 16 * SVW + 4;   // 324
// sO layout strides (f32 units): [c][h16][w16], Sow=17, Soc=273
constexpr int SOW = 17;
constexpr int SOC = 16 * SOW + 1;   // 273
}

// ---------------- pack W/bias into bf16 hi/lo planes [640][512] ----------------
__global__ __launch_bounds__(256) void pack_w(
    const float* __restrict__ Wq, const float* __restrict__ bq,
    const float* __restrict__ Wk, const float* __restrict__ bk,
    const float* __restrict__ Wv, const float* __restrict__ bv,
    short* __restrict__ wpk, float* __restrict__ ball) {
  const int r = blockIdx.x;      // 0..639
  const int t = threadIdx.x;     // 256
  const float* src;
  if (r < 64) {
    src = Wq + (size_t)r * kC;
    if (t == 0) ball[r] = bq[r];
  } else if (r < 128) {
    src = Wk + (size_t)(r - 64) * kC;
    if (t == 0) ball[r] = bk[r - 64];
  } else {
    src = Wv + (size_t)(r - 128) * kC;
    if (t == 0) ball[r] = bv[r - 128];
  }
#pragma unroll
  for (int p = 0; p < 2; ++p) {
    const int c = p * 256 + t;
    const float v = src[c];
    const unsigned short h = f32_to_bf16_rn(v);
    const unsigned short l = f32_to_bf16_rn(v - bf16_to_f32(h));
    wpk[(size_t)r * kC + c] = (short)h;
    wpk[(size_t)kO * kC + (size_t)r * kC + c] = (short)l;
  }
}

// ---------------- pack x (one batch): fp32 [c][l] -> bf16 hi/lo [l][c] ----------------
__global__ __launch_bounds__(256) void pack_x(
    const float* __restrict__ x, short* __restrict__ xpk, int b) {
  __shared__ float sT[64][65];
  const int l0 = blockIdx.x * 64;
  const int c0 = blockIdx.y * 64;
  const int t = threadIdx.x;
  const float* xb = x + (size_t)b * kC * kL;
#pragma unroll
  for (int p = 0; p < 4; ++p) {
    const int ch = p * 256 + t;
    const int c = ch >> 4, l4 = (ch & 15) * 4;
    float4 v = *(const float4*)(xb + (size_t)(c0 + c) * kL + l0 + l4);
    sT[c][l4 + 0] = v.x; sT[c][l4 + 1] = v.y; sT[c][l4 + 2] = v.z; sT[c][l4 + 3] = v.w;
  }
  __syncthreads();
#pragma unroll
  for (int p = 0; p < 2; ++p) {
    const int ch = p * 256 + t;
    const int l = ch >> 3, cg = ch & 7;
    short hi[8], lo[8];
#pragma unroll
    for (int j = 0; j < 8; ++j) {
      const float v = sT[cg * 8 + j][l];
      const unsigned short h = f32_to_bf16_rn(v);
      hi[j] = (short)h;
      lo[j] = (short)f32_to_bf16_rn(v - bf16_to_f32(h));
    }
    short* dh = xpk + (size_t)(l0 + l) * kC + c0 + cg * 8;
    *(bf16x8*)dh = *(bf16x8*)hi;
    *(bf16x8*)(dh + (size_t)kL * kC) = *(bf16x8*)lo;
  }
}

// ---------------- projection GEMM via bf16 MFMA, split precision ----------------
__global__ __launch_bounds__(256, 2) void proj_mfma(
    const short* __restrict__ xpk, const short* __restrict__ wpk,
    const float* __restrict__ ball, float* __restrict__ qkv, int b) {
  __shared__ short A_h[128 * 64];
  __shared__ short A_l[128 * 64];
  __shared__ short B_h[128 * 64];
  __shared__ short B_l[128 * 64];
  const int mt = blockIdx.x;          // 0..4
  const int n0 = blockIdx.y * 128;
  const int m0 = mt * 128;
  const bool qk = (mt == 0);
  const int t = threadIdx.x;
  const int wid = t >> 6, lane = t & 63;
  const int wr = wid >> 1, wc = wid & 1;
  const int lr = lane & 15, lg = lane >> 4;

  f32x4 acc[4][4];
#pragma unroll
  for (int i = 0; i < 4; ++i)
#pragma unroll
    for (int j = 0; j < 4; ++j) acc[i][j] = (f32x4)(0.f);

  for (int kt = 0; kt < 8; ++kt) {
    const int k0 = kt * 64;
#pragma unroll
    for (int p = 0; p < 4; ++p) {
      const int ch = p * 256 + t;
      const int row = ch >> 3, kg = ch & 7;
      const short* src = wpk + (size_t)(m0 + row) * kC + k0 + kg * 8;
      const int off = row * 64 + ((kg ^ (row & 7)) << 3);
      *(bf16x8*)&A_h[off] = *(const bf16x8*)src;
      *(bf16x8*)&A_l[off] = *(const bf16x8*)(src + (size_t)kO * kC);
    }
#pragma unroll
    for (int p = 0; p < 4; ++p) {
      const int ch = p * 256 + t;
      const int row = ch >> 3, kg = ch & 7;
      const short* src = xpk + (size_t)(n0 + row) * kC + k0 + kg * 8;
      const int off = row * 64 + ((kg ^ (row & 7)) << 3);
      *(bf16x8*)&B_h[off] = *(const bf16x8*)src;
      if (qk) *(bf16x8*)&B_l[off] = *(const bf16x8*)(src + (size_t)kL * kC);
    }
    __syncthreads();
#pragma unroll
    for (int ks = 0; ks < 2; ++ks) {
      bf16x8 ah[4], al[4], bh[4], bl[4];
#pragma unroll
      for (int mf = 0; mf < 4; ++mf) {
        const int row = wr * 64 + mf * 16 + lr;
        const int kg = ks * 4 + lg;
        const int off = row * 64 + ((kg ^ (row & 7)) << 3);
        ah[mf] = *(const bf16x8*)&A_h[off];
        al[mf] = *(const bf16x8*)&A_l[off];
      }
#pragma unroll
      for (int nf = 0; nf < 4; ++nf) {
        const int row = wc * 64 + nf * 16 + lr;
        const int kg = ks * 4 + lg;
        const int off = row * 64 + ((kg ^ (row & 7)) << 3);
        bh[nf] = *(const bf16x8*)&B_h[off];
        if (qk) bl[nf] = *(const bf16x8*)&B_l[off];
      }
#pragma unroll
      for (int mf = 0; mf < 4; ++mf)
#pragma unroll
        for (int nf = 0; nf < 4; ++nf) {
          acc[mf][nf] = __builtin_amdgcn_mfma_f32_16x16x32_bf16(
              ah[mf], bh[nf], acc[mf][nf], 0, 0, 0);
          acc[mf][nf] = __builtin_amdgcn_mfma_f32_16x16x32_bf16(
              al[mf], bh[nf], acc[mf][nf], 0, 0, 0);
          if (qk)
            acc[mf][nf] = __builtin_amdgcn_mfma_f32_16x16x32_bf16(
                ah[mf], bl[nf], acc[mf][nf], 0, 0, 0);
        }
    }
    __syncthreads();
  }
#pragma unroll
  for (int mf = 0; mf < 4; ++mf) {
#pragma unroll
    for (int r = 0; r < 4; ++r) {
      const int m = m0 + wr * 64 + mf * 16 + lg * 4 + r;
      const float bias = ball[m];
      float* dst = qkv + ((size_t)b * kO + m) * kL + n0 + wc * 64;
#pragma unroll
      for (int nf = 0; nf < 4; ++nf) {
        dst[nf * 16 + lr] = acc[mf][nf][r] + bias;
      }
    }
  }
}

// ---------------- e_row ----------------
__global__ __launch_bounds__(256) void erow_kernel(
    const float* __restrict__ qkv, float* __restrict__ e) {
  __shared__ float sQ[32][128];
  __shared__ float sK[32][128];
  const int bh = blockIdx.x;
  const int b = bh >> 7, h = bh & 127;
  const int t = threadIdx.x;
  const int tx = t & 15, ty = t >> 4;
  float acc[8][8];
#pragma unroll
  for (int i = 0; i < 8; ++i)
#pragma unroll
    for (int j = 0; j < 8; ++j) acc[i][j] = 0.f;

  for (int k0 = 0; k0 < kCQK; k0 += 32) {
#pragma unroll
    for (int p = 0; p < 4; ++p) {
      const int idx = p * 256 + t;
      const int cc = idx >> 5, w4 = (idx & 31) * 4;
      const size_t base = ((size_t)b * kO + k0 + cc) * kL + h * kW + w4;
      *(float4*)&sQ[cc][w4] = *(const float4*)(qkv + base);
      *(float4*)&sK[cc][w4] = *(const float4*)(qkv + base + (size_t)64 * kL);
    }
    __syncthreads();
#pragma unroll
    for (int kk = 0; kk < 32; ++kk) {
      float a[8], bb[8];
      *(float4*)(a + 0) = *(const float4*)&sQ[kk][ty * 8];
      *(float4*)(a + 4) = *(const float4*)&sQ[kk][ty * 8 + 4];
      *(float4*)(bb + 0) = *(const float4*)&sK[kk][tx * 8];
      *(float4*)(bb + 4) = *(const float4*)&sK[kk][tx * 8 + 4];
#pragma unroll
      for (int wi = 0; wi < 8; ++wi)
#pragma unroll
        for (int ii = 0; ii < 8; ++ii) acc[wi][ii] = fmaf(a[wi], bb[ii], acc[wi][ii]);
    }
    __syncthreads();
  }
#pragma unroll
  for (int wi = 0; wi < 8; ++wi) {
    const int w = ty * 8 + wi;
    float* dst = e + (((size_t)b * kH + h) * kW + w) * 256 + tx * 8;
    float4 o0 = {acc[wi][0], acc[wi][1], acc[wi][2], acc[wi][3]};
    float4 o1 = {acc[wi][4], acc[wi][5], acc[wi][6], acc[wi][7]};
    *(float4*)(dst + 0) = o0;
    *(float4*)(dst + 4) = o1;
  }
}

// ---------------- e_col ----------------
__global__ __launch_bounds__(256) void ecol_kernel(
    const float* __restrict__ qkv, float* __restrict__ e) {
  __shared__ float sQ[32][128];
  __shared__ float sK[32][128];
  const int bw = blockIdx.x;
  const int b = bw >> 7, w = bw & 127;
  const int t = threadIdx.x;
  const int tx = t & 15, ty = t >> 4;
  float acc[8][8];
#pragma unroll
  for (int i = 0; i < 8; ++i)
#pragma unroll
    for (int j = 0; j < 8; ++j) acc[i][j] = 0.f;

  for (int k0 = 0; k0 < kCQK; k0 += 32) {
#pragma unroll
    for (int p = 0; p < 16; ++p) {
      const int idx = p * 256 + t;
      const int cc = idx >> 7, hh = idx & 127;
      const size_t base = ((size_t)b * kO + k0 + cc) * kL + hh * kW + w;
      sQ[cc][hh] = qkv[base];
      sK[cc][hh] = qkv[base + (size_t)64 * kL];
    }
    __syncthreads();
#pragma unroll
    for (int kk = 0; kk < 32; ++kk) {
      float a[8], bb[8];
      *(float4*)(a + 0) = *(const float4*)&sQ[kk][ty * 8];
      *(float4*)(a + 4) = *(const float4*)&sQ[kk][ty * 8 + 4];
      *(float4*)(bb + 0) = *(const float4*)&sK[kk][tx * 8];
      *(float4*)(bb + 4) = *(const float4*)&sK[kk][tx * 8 + 4];
#pragma unroll
      for (int hi = 0; hi < 8; ++hi)
#pragma unroll
        for (int ji = 0; ji < 8; ++ji) acc[hi][ji] = fmaf(a[hi], bb[ji], acc[hi][ji]);
    }
    __syncthreads();
  }
  const float NEG_INF = __int_as_float(0xff800000);
#pragma unroll
  for (int hi = 0; hi < 8; ++hi) {
    const int h = ty * 8 + hi;
    float vals[8];
#pragma unroll
    for (int ji = 0; ji < 8; ++ji) {
      const int j = tx * 8 + ji;
      vals[ji] = (j == h) ? NEG_INF : acc[hi][ji];
    }
    float* dst = e + (((size_t)b * kH + h) * kW + w) * 256 + 128 + tx * 8;
    float4 o0 = {vals[0], vals[1], vals[2], vals[3]};
    float4 o1 = {vals[4], vals[5], vals[6], vals[7]};
    *(float4*)(dst + 0) = o0;
    *(float4*)(dst + 4) = o1;
  }
}

// ---------------- softmax; row half -> fp32 in place, col half -> bf16 afrag ----
// afrag[b][w][jb 4][hb 8][lane 64][8] in the dead q/k region (frag order so
// colagg's B-fragment loads are perfectly contiguous).
__global__ __launch_bounds__(256) void softmax_kernel(
    float* __restrict__ e, float* qkv_base) {
  const int t = threadIdx.x;
  const int wv = t >> 6, lane = t & 63;
  const size_t pix = (size_t)blockIdx.x * 4 + wv;
  float* p = e + pix * 256 + lane * 4;
  float4 v = *(const float4*)p;
  float m = fmaxf(fmaxf(v.x, v.y), fmaxf(v.z, v.w));
#pragma unroll
  for (int off = 32; off > 0; off >>= 1) m = fmaxf(m, __shfl_xor(m, off, 64));
  float e0 = expf(v.x - m), e1 = expf(v.y - m), e2 = expf(v.z - m), e3 = expf(v.w - m);
  float s = e0 + e1 + e2 + e3;
#pragma unroll
  for (int off = 32; off > 0; off >>= 1) s += __shfl_xor(s, off, 64);
  const float inv = 1.0f / s;
  const float o0 = e0 * inv, o1 = e1 * inv, o2 = e2 * inv, o3 = e3 * inv;
  if (lane < 32) {
    float4 o = {o0, o1, o2, o3};
    *(float4*)p = o;                           // a_row stays fp32
  } else {
    const int b = (int)(pix >> 14);
    const int h = (int)((pix >> 7) & 127);
    const int w = (int)(pix & 127);
    const int s32 = lane - 32;        // j = 4*s32 .. +3
    const int jb = s32 >> 3;          // j >> 5
    const int lg = (s32 >> 1) & 3;    // (j >> 3) & 3
    const int eoff = (s32 & 1) * 4;   // j & 7 base
    const int hb = h >> 4, hr = h & 15;
    unsigned short* base = (unsigned short*)qkv_base + (size_t)b * kO * kL * 2
        + (size_t)w * 16384;
    unsigned short* dst =
        base + (((size_t)(jb * 8 + hb) * 64 + lg * 16 + hr) * 8 + eoff);
    *(uint2*)dst = make_uint2(pack_bf16x2(o0, o1), pack_bf16x2(o2, o3));
  }
}

// ---------------- row aggregation (fp32) ----------------
__global__ __launch_bounds__(256) void rowagg_kernel(
    const float* __restrict__ qkv, const float* __restrict__ e,
    float* __restrict__ out) {
  __shared__ float sV[32][132];
  __shared__ float sA[32][132];
  const int bh = blockIdx.y;
  const int b = bh >> 7, h = bh & 127;
  const int m0 = blockIdx.x * 128;
  const int t = threadIdx.x;
  const int tx = t & 15, ty = t >> 4;
  float acc[8][8];
#pragma unroll
  for (int i = 0; i < 8; ++i)
#pragma unroll
    for (int j = 0; j < 8; ++j) acc[i][j] = 0.f;

  for (int i0 = 0; i0 < kW; i0 += 32) {
    {
      const int c = t >> 1, ih = (t & 1) * 16;
      const float* src =
          qkv + ((size_t)b * kO + 128 + m0 + c) * kL + h * kW + i0 + ih;
      float tmp[16];
      *(float4*)(tmp + 0)  = *(const float4*)(src + 0);
      *(float4*)(tmp + 4)  = *(const float4*)(src + 4);
      *(float4*)(tmp + 8)  = *(const float4*)(src + 8);
      *(float4*)(tmp + 12) = *(const float4*)(src + 12);
#pragma unroll
      for (int r = 0; r < 16; ++r) sV[ih + r][c] = tmp[r];
    }
#pragma unroll
    for (int p = 0; p < 4; ++p) {
      const int idx = p * 256 + t;
      const int ww = idx >> 3, q = idx & 7;
      float4 av = *(const float4*)(
          e + (((size_t)b * kH + h) * kW + ww) * 256 + i0 + q * 4);
      sA[q * 4 + 0][ww] = av.x;
      sA[q * 4 + 1][ww] = av.y;
      sA[q * 4 + 2][ww] = av.z;
      sA[q * 4 + 3][ww] = av.w;
    }
    __syncthreads();
#pragma unroll
    for (int kk = 0; kk < 32; ++kk) {
      float a[8], bb[8];
      *(float4*)(a + 0) = *(const float4*)&sV[kk][ty * 8];
      *(float4*)(a + 4) = *(const float4*)&sV[kk][ty * 8 + 4];
      *(float4*)(bb + 0) = *(const float4*)&sA[kk][tx * 8];
      *(float4*)(bb + 4) = *(const float4*)&sA[kk][tx * 8 + 4];
#pragma unroll
      for (int ci = 0; ci < 8; ++ci)
#pragma unroll
        for (int wi = 0; wi < 8; ++wi) acc[ci][wi] = fmaf(a[ci], bb[wi], acc[ci][wi]);
    }
    __syncthreads();
  }
#pragma unroll
  for (int ci = 0; ci < 8; ++ci) {
    const int c = m0 + ty * 8 + ci;
    float* dst = out + (((size_t)b * kC + c) * kH + h) * kW + tx * 8;
    float4 o0 = {acc[ci][0], acc[ci][1], acc[ci][2], acc[ci][3]};
    float4 o1 = {acc[ci][4], acc[ci][5], acc[ci][6], acc[ci][7]};
    *(float4*)(dst + 0) = o0;
    *(float4*)(dst + 4) = o1;
  }
}

// ---------------- col aggregation via bf16 MFMA (v4: all-coalesced, w16) ----------------
// out[b][c][h][w] += sum_j afrag(h,w,j) * v[b][c][j][w]
// Block: 1024 threads = 16 waves; wave wv owns w = w0 + wv.
// V: coalesced float4 loads (lane-adjacent w) -> LDS bf16 j-pairs (padded, 2-way).
// A: direct global bf16x8 frag loads (fragment-order layout, fully contiguous).
// Epilogue: acc -> LDS transpose -> lane-adjacent-w scalar RMW (full lines).
__global__ __launch_bounds__(1024) void colagg_mfma(
    const float* qkv, float* __restrict__ out) {
  __shared__ unsigned sV[64 * SVC];   // 82,944 B; reused as sO (f32) in epilogue
  const int gx = blockIdx.x;          // ct(8) + 8*ht(2)
  const int ct = gx & 7, ht = gx >> 3;
  const int c0 = ct * 64, h0 = ht * 64;
  const int w0 = blockIdx.y * 16;
  const int b = blockIdx.z;
  const int t = threadIdx.x;          // 0..1023
  const int wv = t >> 6, lane = t & 63;
  const int lr = lane & 15, lg = lane >> 4;

  f32x4 acc[4][4];   // [mf(c)][nf(h)]
#pragma unroll
  for (int i = 0; i < 4; ++i)
#pragma unroll
    for (int j = 0; j < 4; ++j) acc[i][j] = (f32x4)(0.f);

  const float* vbase = qkv + ((size_t)b * kO + 128 + c0) * kL + w0;
  const unsigned short* ab = (const unsigned short*)qkv + (size_t)b * kO * kL * 2
      + (size_t)(w0 + wv) * 16384;

  // V staging roles: c-group = wave, j-pair = (t>>2)&15, w-quad = t&3
  const int vjp = (t >> 2) & 15;
  const int vwq = t & 3;
  const int vjq = vjp >> 2, vjr = vjp & 3;

  for (int kt = 0; kt < 4; ++kt) {
    const int j0 = kt * 32;
    // ---- stage V (coalesced: 4 lanes = 64B line) ----
#pragma unroll
    for (int i = 0; i < 4; ++i) {
      const int c = wv * 4 + i;
      const float* src = vbase + (size_t)c * kL + (size_t)(j0 + 2 * vjp) * kW + vwq * 4;
      float4 v0 = *(const float4*)src;          // j even, 4 w's
      float4 v1 = *(const float4*)(src + kW);   // j odd
      unsigned* d = sV + c * SVC + vjq * 4 + vjr;
      d[(vwq * 4 + 0) * SVW] = pack_bf16x2(v0.x, v1.x);
      d[(vwq * 4 + 1) * SVW] = pack_bf16x2(v0.y, v1.y);
      d[(vwq * 4 + 2) * SVW] = pack_bf16x2(v0.z, v1.z);
      d[(vwq * 4 + 3) * SVW] = pack_bf16x2(v0.w, v1.w);
    }
    // ---- A frags: direct, perfectly contiguous (1KB per wave-instr) ----
    bf16x8 af[4];
#pragma unroll
    for (int nf = 0; nf < 4; ++nf) {
      af[nf] = *(const bf16x8*)(
          ab + (((size_t)(kt * 8 + ht * 4 + nf) * 64 + lane) * 8));
    }
    __syncthreads();
    bf16x8 vf[4];
#pragma unroll
    for (int mf = 0; mf < 4; ++mf) {
      const int c = mf * 16 + lr;
      vf[mf] = *(const bf16x8*)&sV[c * SVC + wv * SVW + lg * 4];
    }
#pragma unroll
    for (int mf = 0; mf < 4; ++mf)
#pragma unroll
      for (int nf = 0; nf < 4; ++nf)
        acc[mf][nf] = __builtin_amdgcn_mfma_f32_16x16x32_bf16(
            vf[mf], af[nf], acc[mf][nf], 0, 0, 0);
    __syncthreads();
  }

  // ---- epilogue: LDS transpose + fully-coalesced scalar RMW ----
  float* sO = (float*)sV;   // 64*SOC*4B = 69,888B <= 82,944B
  const int ew = t & 15, ehh = (t >> 4) & 15, ecb = t >> 8;   // w, h, c-low
  for (int nf = 0; nf < 4; ++nf) {
    // wave wv writes its w-slot: sO[c][h][wv], D row=c(4lg+r), col=h(lr)
#pragma unroll
    for (int mf = 0; mf < 4; ++mf)
#pragma unroll
      for (int r = 0; r < 4; ++r)
        sO[(mf * 16 + lg * 4 + r) * SOC + lr * SOW + wv] = acc[mf][nf][r];
    __syncthreads();
#pragma unroll
    for (int q = 0; q < 16; ++q) {
      const int c = q * 4 + ecb;
      float* dst = out + (((size_t)b * kC + c0 + c) * kH + h0 + nf * 16 + ehh) * kW
          + w0 + ew;
      *dst += sO[c * SOC + ehh * SOW + ew];
    }
    __syncthreads();
  }
}

extern "C" void kernel_launch(void* const* d_in, const int* in_sizes, int n_in,
                              void* d_out, int out_size, void* d_ws, size_t ws_size,
                              hipStream_t stream) {
  (void)in_sizes; (void)n_in; (void)out_size; (void)ws_size;
  const float* x  = (const float*)d_in[0];
  const float* Wq = (const float*)d_in[1];
  const float* bq = (const float*)d_in[2];
  const float* Wk = (const float*)d_in[3];
  const float* bk = (const float*)d_in[4];
  const float* Wv = (const float*)d_in[5];
  const float* bv = (const float*)d_in[6];
  float* out = (float*)d_out;
  float* ws  = (float*)d_ws;

  short* wpk = (short*)(ws + OFF_WALL);
  float* ball = ws + OFF_BALL;
  float* qkv  = ws + OFF_QKV;
  float* e    = ws + OFF_E;
  short* xpk  = (short*)(ws + OFF_E);   // aliases e (used only before e is written)

  pack_w<<<dim3(kO), dim3(256), 0, stream>>>(Wq, bq, Wk, bk, Wv, bv, wpk, ball);
  for (int b = 0; b < kB; ++b) {
    pack_x<<<dim3(kL / 64, kC / 64), dim3(256), 0, stream>>>(x, xpk, b);
    proj_mfma<<<dim3(5, kL / 128), dim3(256), 0, stream>>>(xpk, wpk, ball, qkv, b);
  }
  erow_kernel<<<dim3(kB * kH), dim3(256), 0, stream>>>(qkv, e);
  ecol_kernel<<<dim3(kB * kW), dim3(256), 0, stream>>>(qkv, e);
  softmax_kernel<<<dim3(kB * kH * kW / 4), dim3(256), 0, stream>>>(e, qkv);
  rowagg_kernel<<<dim3(kC / 128, kB * kH), dim3(256), 0, stream>>>(qkv, e, out);
  colagg_mfma<<<dim3(16, kW / 16, kB), dim3(1024), 0, stream>>>(qkv, out);
}

// Round 7
// 596.035 us; speedup vs baseline: 1.4118x; 1.0927x over previous
//
#include <hip/hip_runtime.h>
#include <hip/hip_bf16.h>

namespace {
constexpr int kB = 4;
constexpr int kC = 512;
constexpr int kH = 128;
constexpr int kW = 128;
constexpr int kCQK = 64;
constexpr int kL = kH * kW;   // 16384
constexpr int kO = 640;       // rows: [0,64)=Wq, [64,128)=Wk, [128,640)=Wv

// workspace layout (float offsets)
constexpr size_t OFF_WALL = 0;                          // wpk: 640*512*2 bf16
constexpr size_t OFF_BALL = (size_t)kO * kC;            // 640
constexpr size_t OFF_QKV  = OFF_BALL + kO;              // B*640*L fp32
constexpr size_t OFF_E    = OFF_QKV + (size_t)kB * kO * kL;  // B*H*W*256 fp32
constexpr size_t WS_FLOATS = OFF_E + (size_t)kB * kH * kW * 256;
// After ecol, the q/k rows of qkv (first 128 rows/batch = 8.4MB/b) are dead.
// softmax fills them with (u16 units, per batch):
//   [0 .. 2097152)        afrag[w][jb 4][hb 8][lane 64][8]   (col weights, frag order)
//   [2097152 .. 4194304)  arowT[h][w][i 128]                 (row weights, i-contig)

typedef __attribute__((ext_vector_type(8))) short bf16x8;
typedef __attribute__((ext_vector_type(4))) float f32x4;

__device__ __forceinline__ unsigned short f32_to_bf16_rn(float f) {
  unsigned u = __float_as_uint(f);
  unsigned r = (u + 0x7FFFu + ((u >> 16) & 1u)) >> 16;
  return (unsigned short)r;
}
__device__ __forceinline__ float bf16_to_f32(unsigned short h) {
  return __uint_as_float(((unsigned)h) << 16);
}
__device__ __forceinline__ unsigned pack_bf16x2(float a, float b) {
  return (unsigned)f32_to_bf16_rn(a) | ((unsigned)f32_to_bf16_rn(b) << 16);
}
// colagg sV layout strides (u32 units): [c][w][jq][jr], Sw=20, Sc=324
constexpr int SVW = 20;
constexpr int SVC = 16 * SVW + 4;   // 324
// colagg sO layout strides (f32 units): [c][h16][w16]
constexpr int SOW = 17;
constexpr int SOC = 16 * SOW + 1;   // 273
constexpr size_t AROWT_OFF = 2097152;   // u16 offset within q/k region
}

// ---------------- pack W/bias into bf16 hi/lo planes [640][512] ----------------
__global__ __launch_bounds__(256) void pack_w(
    const float* __restrict__ Wq, const float* __restrict__ bq,
    const float* __restrict__ Wk, const float* __restrict__ bk,
    const float* __restrict__ Wv, const float* __restrict__ bv,
    short* __restrict__ wpk, float* __restrict__ ball) {
  const int r = blockIdx.x;      // 0..639
  const int t = threadIdx.x;     // 256
  const float* src;
  if (r < 64) {
    src = Wq + (size_t)r * kC;
    if (t == 0) ball[r] = bq[r];
  } else if (r < 128) {
    src = Wk + (size_t)(r - 64) * kC;
    if (t == 0) ball[r] = bk[r - 64];
  } else {
    src = Wv + (size_t)(r - 128) * kC;
    if (t == 0) ball[r] = bv[r - 128];
  }
#pragma unroll
  for (int p = 0; p < 2; ++p) {
    const int c = p * 256 + t;
    const float v = src[c];
    const unsigned short h = f32_to_bf16_rn(v);
    const unsigned short l = f32_to_bf16_rn(v - bf16_to_f32(h));
    wpk[(size_t)r * kC + c] = (short)h;
    wpk[(size_t)kO * kC + (size_t)r * kC + c] = (short)l;
  }
}

// ---------------- pack x (one batch): fp32 [c][l] -> bf16 hi/lo [l][c] ----------------
__global__ __launch_bounds__(256) void pack_x(
    const float* __restrict__ x, short* __restrict__ xpk, int b) {
  __shared__ float sT[64][65];
  const int l0 = blockIdx.x * 64;
  const int c0 = blockIdx.y * 64;
  const int t = threadIdx.x;
  const float* xb = x + (size_t)b * kC * kL;
#pragma unroll
  for (int p = 0; p < 4; ++p) {
    const int ch = p * 256 + t;
    const int c = ch >> 4, l4 = (ch & 15) * 4;
    float4 v = *(const float4*)(xb + (size_t)(c0 + c) * kL + l0 + l4);
    sT[c][l4 + 0] = v.x; sT[c][l4 + 1] = v.y; sT[c][l4 + 2] = v.z; sT[c][l4 + 3] = v.w;
  }
  __syncthreads();
#pragma unroll
  for (int p = 0; p < 2; ++p) {
    const int ch = p * 256 + t;
    const int l = ch >> 3, cg = ch & 7;
    short hi[8], lo[8];
#pragma unroll
    for (int j = 0; j < 8; ++j) {
      const float v = sT[cg * 8 + j][l];
      const unsigned short h = f32_to_bf16_rn(v);
      hi[j] = (short)h;
      lo[j] = (short)f32_to_bf16_rn(v - bf16_to_f32(h));
    }
    short* dh = xpk + (size_t)(l0 + l) * kC + c0 + cg * 8;
    *(bf16x8*)dh = *(bf16x8*)hi;
    *(bf16x8*)(dh + (size_t)kL * kC) = *(bf16x8*)lo;
  }
}

// ---------------- projection GEMM via bf16 MFMA, split precision ----------------
__global__ __launch_bounds__(256, 2) void proj_mfma(
    const short* __restrict__ xpk, const short* __restrict__ wpk,
    const float* __restrict__ ball, float* __restrict__ qkv, int b) {
  __shared__ short A_h[128 * 64];
  __shared__ short A_l[128 * 64];
  __shared__ short B_h[128 * 64];
  __shared__ short B_l[128 * 64];
  const int mt = blockIdx.x;          // 0..4
  const int n0 = blockIdx.y * 128;
  const int m0 = mt * 128;
  const bool qk = (mt == 0);
  const int t = threadIdx.x;
  const int wid = t >> 6, lane = t & 63;
  const int wr = wid >> 1, wc = wid & 1;
  const int lr = lane & 15, lg = lane >> 4;

  f32x4 acc[4][4];
#pragma unroll
  for (int i = 0; i < 4; ++i)
#pragma unroll
    for (int j = 0; j < 4; ++j) acc[i][j] = (f32x4)(0.f);

  for (int kt = 0; kt < 8; ++kt) {
    const int k0 = kt * 64;
#pragma unroll
    for (int p = 0; p < 4; ++p) {
      const int ch = p * 256 + t;
      const int row = ch >> 3, kg = ch & 7;
      const short* src = wpk + (size_t)(m0 + row) * kC + k0 + kg * 8;
      const int off = row * 64 + ((kg ^ (row & 7)) << 3);
      *(bf16x8*)&A_h[off] = *(const bf16x8*)src;
      *(bf16x8*)&A_l[off] = *(const bf16x8*)(src + (size_t)kO * kC);
    }
#pragma unroll
    for (int p = 0; p < 4; ++p) {
      const int ch = p * 256 + t;
      const int row = ch >> 3, kg = ch & 7;
      const short* src = xpk + (size_t)(n0 + row) * kC + k0 + kg * 8;
      const int off = row * 64 + ((kg ^ (row & 7)) << 3);
      *(bf16x8*)&B_h[off] = *(const bf16x8*)src;
      if (qk) *(bf16x8*)&B_l[off] = *(const bf16x8*)(src + (size_t)kL * kC);
    }
    __syncthreads();
#pragma unroll
    for (int ks = 0; ks < 2; ++ks) {
      bf16x8 ah[4], al[4], bh[4], bl[4];
#pragma unroll
      for (int mf = 0; mf < 4; ++mf) {
        const int row = wr * 64 + mf * 16 + lr;
        const int kg = ks * 4 + lg;
        const int off = row * 64 + ((kg ^ (row & 7)) << 3);
        ah[mf] = *(const bf16x8*)&A_h[off];
        al[mf] = *(const bf16x8*)&A_l[off];
      }
#pragma unroll
      for (int nf = 0; nf < 4; ++nf) {
        const int row = wc * 64 + nf * 16 + lr;
        const int kg = ks * 4 + lg;
        const int off = row * 64 + ((kg ^ (row & 7)) << 3);
        bh[nf] = *(const bf16x8*)&B_h[off];
        if (qk) bl[nf] = *(const bf16x8*)&B_l[off];
      }
#pragma unroll
      for (int mf = 0; mf < 4; ++mf)
#pragma unroll
        for (int nf = 0; nf < 4; ++nf) {
          acc[mf][nf] = __builtin_amdgcn_mfma_f32_16x16x32_bf16(
              ah[mf], bh[nf], acc[mf][nf], 0, 0, 0);
          acc[mf][nf] = __builtin_amdgcn_mfma_f32_16x16x32_bf16(
              al[mf], bh[nf], acc[mf][nf], 0, 0, 0);
          if (qk)
            acc[mf][nf] = __builtin_amdgcn_mfma_f32_16x16x32_bf16(
                ah[mf], bl[nf], acc[mf][nf], 0, 0, 0);
        }
    }
    __syncthreads();
  }
#pragma unroll
  for (int mf = 0; mf < 4; ++mf) {
#pragma unroll
    for (int r = 0; r < 4; ++r) {
      const int m = m0 + wr * 64 + mf * 16 + lg * 4 + r;
      const float bias = ball[m];
      float* dst = qkv + ((size_t)b * kO + m) * kL + n0 + wc * 64;
#pragma unroll
      for (int nf = 0; nf < 4; ++nf) {
        dst[nf * 16 + lr] = acc[mf][nf][r] + bias;
      }
    }
  }
}

// ---------------- e_row ----------------
__global__ __launch_bounds__(256) void erow_kernel(
    const float* __restrict__ qkv, float* __restrict__ e) {
  __shared__ float sQ[32][128];
  __shared__ float sK[32][128];
  const int bh = blockIdx.x;
  const int b = bh >> 7, h = bh & 127;
  const int t = threadIdx.x;
  const int tx = t & 15, ty = t >> 4;
  float acc[8][8];
#pragma unroll
  for (int i = 0; i < 8; ++i)
#pragma unroll
    for (int j = 0; j < 8; ++j) acc[i][j] = 0.f;

  for (int k0 = 0; k0 < kCQK; k0 += 32) {
#pragma unroll
    for (int p = 0; p < 4; ++p) {
      const int idx = p * 256 + t;
      const int cc = idx >> 5, w4 = (idx & 31) * 4;
      const size_t base = ((size_t)b * kO + k0 + cc) * kL + h * kW + w4;
      *(float4*)&sQ[cc][w4] = *(const float4*)(qkv + base);
      *(float4*)&sK[cc][w4] = *(const float4*)(qkv + base + (size_t)64 * kL);
    }
    __syncthreads();
#pragma unroll
    for (int kk = 0; kk < 32; ++kk) {
      float a[8], bb[8];
      *(float4*)(a + 0) = *(const float4*)&sQ[kk][ty * 8];
      *(float4*)(a + 4) = *(const float4*)&sQ[kk][ty * 8 + 4];
      *(float4*)(bb + 0) = *(const float4*)&sK[kk][tx * 8];
      *(float4*)(bb + 4) = *(const float4*)&sK[kk][tx * 8 + 4];
#pragma unroll
      for (int wi = 0; wi < 8; ++wi)
#pragma unroll
        for (int ii = 0; ii < 8; ++ii) acc[wi][ii] = fmaf(a[wi], bb[ii], acc[wi][ii]);
    }
    __syncthreads();
  }
#pragma unroll
  for (int wi = 0; wi < 8; ++wi) {
    const int w = ty * 8 + wi;
    float* dst = e + (((size_t)b * kH + h) * kW + w) * 256 + tx * 8;
    float4 o0 = {acc[wi][0], acc[wi][1], acc[wi][2], acc[wi][3]};
    float4 o1 = {acc[wi][4], acc[wi][5], acc[wi][6], acc[wi][7]};
    *(float4*)(dst + 0) = o0;
    *(float4*)(dst + 4) = o1;
  }
}

// ---------------- e_col ----------------
__global__ __launch_bounds__(256) void ecol_kernel(
    const float* __restrict__ qkv, float* __restrict__ e) {
  __shared__ float sQ[32][128];
  __shared__ float sK[32][128];
  const int bw = blockIdx.x;
  const int b = bw >> 7, w = bw & 127;
  const int t = threadIdx.x;
  const int tx = t & 15, ty = t >> 4;
  float acc[8][8];
#pragma unroll
  for (int i = 0; i < 8; ++i)
#pragma unroll
    for (int j = 0; j < 8; ++j) acc[i][j] = 0.f;

  for (int k0 = 0; k0 < kCQK; k0 += 32) {
#pragma unroll
    for (int p = 0; p < 16; ++p) {
      const int idx = p * 256 + t;
      const int cc = idx >> 7, hh = idx & 127;
      const size_t base = ((size_t)b * kO + k0 + cc) * kL + hh * kW + w;
      sQ[cc][hh] = qkv[base];
      sK[cc][hh] = qkv[base + (size_t)64 * kL];
    }
    __syncthreads();
#pragma unroll
    for (int kk = 0; kk < 32; ++kk) {
      float a[8], bb[8];
      *(float4*)(a + 0) = *(const float4*)&sQ[kk][ty * 8];
      *(float4*)(a + 4) = *(const float4*)&sQ[kk][ty * 8 + 4];
      *(float4*)(bb + 0) = *(const float4*)&sK[kk][tx * 8];
      *(float4*)(bb + 4) = *(const float4*)&sK[kk][tx * 8 + 4];
#pragma unroll
      for (int hi = 0; hi < 8; ++hi)
#pragma unroll
        for (int ji = 0; ji < 8; ++ji) acc[hi][ji] = fmaf(a[hi], bb[ji], acc[hi][ji]);
    }
    __syncthreads();
  }
  const float NEG_INF = __int_as_float(0xff800000);
#pragma unroll
  for (int hi = 0; hi < 8; ++hi) {
    const int h = ty * 8 + hi;
    float vals[8];
#pragma unroll
    for (int ji = 0; ji < 8; ++ji) {
      const int j = tx * 8 + ji;
      vals[ji] = (j == h) ? NEG_INF : acc[hi][ji];
    }
    float* dst = e + (((size_t)b * kH + h) * kW + w) * 256 + 128 + tx * 8;
    float4 o0 = {vals[0], vals[1], vals[2], vals[3]};
    float4 o1 = {vals[4], vals[5], vals[6], vals[7]};
    *(float4*)(dst + 0) = o0;
    *(float4*)(dst + 4) = o1;
  }
}

// ---------------- softmax; row half -> bf16 arowT, col half -> bf16 afrag ----
// (no fp32 writeback to e — nothing reads e after this kernel)
__global__ __launch_bounds__(256) void softmax_kernel(
    float* __restrict__ e, float* qkv_base) {
  const int t = threadIdx.x;
  const int wv = t >> 6, lane = t & 63;
  const size_t pix = (size_t)blockIdx.x * 4 + wv;
  float* p = e + pix * 256 + lane * 4;
  float4 v = *(const float4*)p;
  float m = fmaxf(fmaxf(v.x, v.y), fmaxf(v.z, v.w));
#pragma unroll
  for (int off = 32; off > 0; off >>= 1) m = fmaxf(m, __shfl_xor(m, off, 64));
  float e0 = expf(v.x - m), e1 = expf(v.y - m), e2 = expf(v.z - m), e3 = expf(v.w - m);
  float s = e0 + e1 + e2 + e3;
#pragma unroll
  for (int off = 32; off > 0; off >>= 1) s += __shfl_xor(s, off, 64);
  const float inv = 1.0f / s;
  const float o0 = e0 * inv, o1 = e1 * inv, o2 = e2 * inv, o3 = e3 * inv;
  const int b = (int)(pix >> 14);
  const int h = (int)((pix >> 7) & 127);
  const int w = (int)(pix & 127);
  unsigned short* base = (unsigned short*)qkv_base + (size_t)b * kO * kL * 2;
  if (lane < 32) {
    // a_row -> arowT[h][w][i], i = lane*4 (contiguous 256B per pixel)
    unsigned short* dst = base + AROWT_OFF + (((size_t)h * kW + w) * 128 + lane * 4);
    *(uint2*)dst = make_uint2(pack_bf16x2(o0, o1), pack_bf16x2(o2, o3));
  } else {
    // a_col -> afrag (fragment order for colagg's direct B-frag loads)
    const int s32 = lane - 32;        // j = 4*s32 .. +3
    const int jb = s32 >> 3;
    const int lg = (s32 >> 1) & 3;
    const int eoff = (s32 & 1) * 4;
    const int hb = h >> 4, hr = h & 15;
    unsigned short* dst = base + (size_t)w * 16384
        + (((size_t)(jb * 8 + hb) * 64 + lg * 16 + hr) * 8 + eoff);
    *(uint2*)dst = make_uint2(pack_bf16x2(o0, o1), pack_bf16x2(o2, o3));
  }
}

// ---------------- row aggregation via bf16 MFMA ----------------
// out[b][c][h][w] = sum_i arowT[b][h][w][i] * v[b][c][h][i]
// Block: 256 thr = 4 waves (2x2); M=128 c, N=128 w, K=128 i (2 steps of 64).
// V' staged to LDS bf16 (proj-style XOR swizzle); A(row-weight) frags direct
// from global arowT (w-rows 256B apart, all 4 lg-groups pack each line).
// Epilogue: plain stores, 64 consecutive w per (mf,r) -> fully coalesced.
__global__ __launch_bounds__(256) void rowagg_mfma(
    const float* qkv, float* __restrict__ out) {
  __shared__ short sV[128 * 64];   // [c][i] bf16, swizzled, 16KB
  const int ct = blockIdx.x;       // 0..3 (c-tile; fastest -> arow L2 reuse)
  const int bh = blockIdx.y;
  const int b = bh >> 7, h = bh & 127;
  const int c0 = ct * 128;
  const int t = threadIdx.x;
  const int wid = t >> 6, lane = t & 63;
  const int wr = wid >> 1, wc = wid & 1;
  const int lr = lane & 15, lg = lane >> 4;

  f32x4 acc[4][4];   // [mf(c)][nf(w)]
#pragma unroll
  for (int i = 0; i < 4; ++i)
#pragma unroll
    for (int j = 0; j < 4; ++j) acc[i][j] = (f32x4)(0.f);

  const float* vbase = qkv + ((size_t)b * kO + 128 + c0) * kL + (size_t)h * kW;
  const unsigned short* arbase = (const unsigned short*)qkv
      + (size_t)b * kO * kL * 2 + AROWT_OFF + (size_t)h * kW * 128;

  for (int kt = 0; kt < 2; ++kt) {
    const int i0 = kt * 64;
    // ---- stage V': row c = t>>1, i-half = (t&1)*32; 8 float4 -> 4 swizzled groups
    {
      const int c = t >> 1;
      const int half = t & 1;
      const float* src = vbase + (size_t)c * kL + i0 + half * 32;
#pragma unroll
      for (int q = 0; q < 4; ++q) {
        const int g = half * 4 + q;               // i-group 0..7 (8 bf16 each)
        float4 a0 = *(const float4*)(src + q * 8);
        float4 a1 = *(const float4*)(src + q * 8 + 4);
        unsigned* d = (unsigned*)&sV[c * 64 + ((g ^ (c & 7)) << 3)];
        d[0] = pack_bf16x2(a0.x, a0.y);
        d[1] = pack_bf16x2(a0.z, a0.w);
        d[2] = pack_bf16x2(a1.x, a1.y);
        d[3] = pack_bf16x2(a1.z, a1.w);
      }
    }
    __syncthreads();
#pragma unroll
    for (int ks = 0; ks < 2; ++ks) {
      bf16x8 vfr[4], afr[4];
#pragma unroll
      for (int mf = 0; mf < 4; ++mf) {
        const int row = wr * 64 + mf * 16 + lr;
        const int kg = ks * 4 + lg;
        vfr[mf] = *(const bf16x8*)&sV[row * 64 + ((kg ^ (row & 7)) << 3)];
      }
#pragma unroll
      for (int nf = 0; nf < 4; ++nf) {
        const int w = wc * 64 + nf * 16 + lr;
        afr[nf] = *(const bf16x8*)(arbase + (size_t)w * 128 + i0 + ks * 32 + lg * 8);
      }
#pragma unroll
      for (int mf = 0; mf < 4; ++mf)
#pragma unroll
        for (int nf = 0; nf < 4; ++nf)
          acc[mf][nf] = __builtin_amdgcn_mfma_f32_16x16x32_bf16(
              vfr[mf], afr[nf], acc[mf][nf], 0, 0, 0);
    }
    __syncthreads();
  }
  // ---- epilogue: D row=c(4lg+r), col=w(lr); stores (colagg RMWs after) ----
#pragma unroll
  for (int mf = 0; mf < 4; ++mf) {
#pragma unroll
    for (int r = 0; r < 4; ++r) {
      const int c = c0 + wr * 64 + mf * 16 + lg * 4 + r;
      float* dst = out + (((size_t)b * kC + c) * kH + h) * kW + wc * 64;
#pragma unroll
      for (int nf = 0; nf < 4; ++nf) {
        dst[nf * 16 + lr] = acc[mf][nf][r];
      }
    }
  }
}

// ---------------- col aggregation via bf16 MFMA (all-coalesced, w16) ----------------
__global__ __launch_bounds__(1024) void colagg_mfma(
    const float* qkv, float* __restrict__ out) {
  __shared__ unsigned sV[64 * SVC];   // 82,944 B; reused as sO (f32) in epilogue
  const int gx = blockIdx.x;          // ct(8) + 8*ht(2)
  const int ct = gx & 7, ht = gx >> 3;
  const int c0 = ct * 64, h0 = ht * 64;
  const int w0 = blockIdx.y * 16;
  const int b = blockIdx.z;
  const int t = threadIdx.x;          // 0..1023
  const int wv = t >> 6, lane = t & 63;
  const int lr = lane & 15, lg = lane >> 4;

  f32x4 acc[4][4];   // [mf(c)][nf(h)]
#pragma unroll
  for (int i = 0; i < 4; ++i)
#pragma unroll
    for (int j = 0; j < 4; ++j) acc[i][j] = (f32x4)(0.f);

  const float* vbase = qkv + ((size_t)b * kO + 128 + c0) * kL + w0;
  const unsigned short* ab = (const unsigned short*)qkv + (size_t)b * kO * kL * 2
      + (size_t)(w0 + wv) * 16384;

  const int vjp = (t >> 2) & 15;
  const int vwq = t & 3;
  const int vjq = vjp >> 2, vjr = vjp & 3;

  for (int kt = 0; kt < 4; ++kt) {
    const int j0 = kt * 32;
#pragma unroll
    for (int i = 0; i < 4; ++i) {
      const int c = wv * 4 + i;
      const float* src = vbase + (size_t)c * kL + (size_t)(j0 + 2 * vjp) * kW + vwq * 4;
      float4 v0 = *(const float4*)src;
      float4 v1 = *(const float4*)(src + kW);
      unsigned* d = sV + c * SVC + vjq * 4 + vjr;
      d[(vwq * 4 + 0) * SVW] = pack_bf16x2(v0.x, v1.x);
      d[(vwq * 4 + 1) * SVW] = pack_bf16x2(v0.y, v1.y);
      d[(vwq * 4 + 2) * SVW] = pack_bf16x2(v0.z, v1.z);
      d[(vwq * 4 + 3) * SVW] = pack_bf16x2(v0.w, v1.w);
    }
    bf16x8 af[4];
#pragma unroll
    for (int nf = 0; nf < 4; ++nf) {
      af[nf] = *(const bf16x8*)(
          ab + (((size_t)(kt * 8 + ht * 4 + nf) * 64 + lane) * 8));
    }
    __syncthreads();
    bf16x8 vf[4];
#pragma unroll
    for (int mf = 0; mf < 4; ++mf) {
      const int c = mf * 16 + lr;
      vf[mf] = *(const bf16x8*)&sV[c * SVC + wv * SVW + lg * 4];
    }
#pragma unroll
    for (int mf = 0; mf < 4; ++mf)
#pragma unroll
      for (int nf = 0; nf < 4; ++nf)
        acc[mf][nf] = __builtin_amdgcn_mfma_f32_16x16x32_bf16(
            vf[mf], af[nf], acc[mf][nf], 0, 0, 0);
    __syncthreads();
  }

  float* sO = (float*)sV;
  const int ew = t & 15, ehh = (t >> 4) & 15, ecb = t >> 8;
  for (int nf = 0; nf < 4; ++nf) {
#pragma unroll
    for (int mf = 0; mf < 4; ++mf)
#pragma unroll
      for (int r = 0; r < 4; ++r)
        sO[(mf * 16 + lg * 4 + r) * SOC + lr * SOW + wv] = acc[mf][nf][r];
    __syncthreads();
#pragma unroll
    for (int q = 0; q < 16; ++q) {
      const int c = q * 4 + ecb;
      float* dst = out + (((size_t)b * kC + c0 + c) * kH + h0 + nf * 16 + ehh) * kW
          + w0 + ew;
      *dst += sO[c * SOC + ehh * SOW + ew];
    }
    __syncthreads();
  }
}

extern "C" void kernel_launch(void* const* d_in, const int* in_sizes, int n_in,
                              void* d_out, int out_size, void* d_ws, size_t ws_size,
                              hipStream_t stream) {
  (void)in_sizes; (void)n_in; (void)out_size; (void)ws_size;
  const float* x  = (const float*)d_in[0];
  const float* Wq = (const float*)d_in[1];
  const float* bq = (const float*)d_in[2];
  const float* Wk = (const float*)d_in[3];
  const float* bk = (const float*)d_in[4];
  const float* Wv = (const float*)d_in[5];
  const float* bv = (const float*)d_in[6];
  float* out = (float*)d_out;
  float* ws  = (float*)d_ws;

  short* wpk = (short*)(ws + OFF_WALL);
  float* ball = ws + OFF_BALL;
  float* qkv  = ws + OFF_QKV;
  float* e    = ws + OFF_E;
  short* xpk  = (short*)(ws + OFF_E);   // aliases e (used only before e is written)

  pack_w<<<dim3(kO), dim3(256), 0, stream>>>(Wq, bq, Wk, bk, Wv, bv, wpk, ball);
  for (int b = 0; b < kB; ++b) {
    pack_x<<<dim3(kL / 64, kC / 64), dim3(256), 0, stream>>>(x, xpk, b);
    proj_mfma<<<dim3(5, kL / 128), dim3(256), 0, stream>>>(xpk, wpk, ball, qkv, b);
  }
  erow_kernel<<<dim3(kB * kH), dim3(256), 0, stream>>>(qkv, e);
  ecol_kernel<<<dim3(kB * kW), dim3(256), 0, stream>>>(qkv, e);
  softmax_kernel<<<dim3(kB * kH * kW / 4), dim3(256), 0, stream>>>(e, qkv);
  rowagg_mfma<<<dim3(4, kB * kH), dim3(256), 0, stream>>>(qkv, out);
  colagg_mfma<<<dim3(16, kW / 16, kB), dim3(1024), 0, stream>>>(qkv, out);
}

// Round 8
// 578.206 us; speedup vs baseline: 1.4553x; 1.0308x over previous
//
#include <hip/hip_runtime.h>
#include <hip/hip_bf16.h>

namespace {
constexpr int kB = 4;
constexpr int kC = 512;
constexpr int kH = 128;
constexpr int kW = 128;
constexpr int kCQK = 64;
constexpr int kL = kH * kW;   // 16384
constexpr int kO = 640;       // rows: [0,64)=Wq, [64,128)=Wk, [128,640)=Wv

// workspace layout (float offsets)
constexpr size_t OFF_WALL = 0;                          // wpk: 640*512*2 bf16
constexpr size_t OFF_BALL = (size_t)kO * kC;            // 640
constexpr size_t OFF_QKV  = OFF_BALL + kO;              // B*640*L fp32
constexpr size_t OFF_E    = OFF_QKV + (size_t)kB * kO * kL;  // B*H*W*256 fp32
constexpr size_t WS_FLOATS = OFF_E + (size_t)kB * kH * kW * 256;
// After ecol, q/k rows of qkv (8.4MB/b) are dead. softmax fills them (u16/b):
//   [0 .. 2097152)        afrag[w][jb 4][hb 8][lane 64][8]   (col weights)
//   [2097152 .. 4194304)  arowT[h][w][i 128]                 (row weights)
// After softmax, e (67MB) is dead. vtrans fills it with
//   vfrag[b][w 128][cb 32][kt 4][lane 64][8] bf16  (V in MFMA-frag order)

typedef __attribute__((ext_vector_type(8))) short bf16x8;
typedef __attribute__((ext_vector_type(4))) float f32x4;

__device__ __forceinline__ unsigned short f32_to_bf16_rn(float f) {
  unsigned u = __float_as_uint(f);
  unsigned r = (u + 0x7FFFu + ((u >> 16) & 1u)) >> 16;
  return (unsigned short)r;
}
__device__ __forceinline__ float bf16_to_f32(unsigned short h) {
  return __uint_as_float(((unsigned)h) << 16);
}
__device__ __forceinline__ unsigned pack_bf16x2(float a, float b) {
  return (unsigned)f32_to_bf16_rn(a) | ((unsigned)f32_to_bf16_rn(b) << 16);
}
// colagg epilogue sO strides (f32 units)
constexpr int SOW = 17;
constexpr int SOC = 16 * SOW + 1;   // 273
constexpr size_t AROWT_OFF = 2097152;   // u16 offset within q/k region
// vtrans LDS strides (f32 units)
constexpr int VT_SC = 68;             // per c (64 j + 4 pad), 16B-aligned
constexpr int VT_SW = 16 * VT_SC + 4; // 1092 per w-plane, 16B-aligned
}

// ---------------- pack W/bias into bf16 hi/lo planes [640][512] ----------------
__global__ __launch_bounds__(256) void pack_w(
    const float* __restrict__ Wq, const float* __restrict__ bq,
    const float* __restrict__ Wk, const float* __restrict__ bk,
    const float* __restrict__ Wv, const float* __restrict__ bv,
    short* __restrict__ wpk, float* __restrict__ ball) {
  const int r = blockIdx.x;      // 0..639
  const int t = threadIdx.x;     // 256
  const float* src;
  if (r < 64) {
    src = Wq + (size_t)r * kC;
    if (t == 0) ball[r] = bq[r];
  } else if (r < 128) {
    src = Wk + (size_t)(r - 64) * kC;
    if (t == 0) ball[r] = bk[r - 64];
  } else {
    src = Wv + (size_t)(r - 128) * kC;
    if (t == 0) ball[r] = bv[r - 128];
  }
#pragma unroll
  for (int p = 0; p < 2; ++p) {
    const int c = p * 256 + t;
    const float v = src[c];
    const unsigned short h = f32_to_bf16_rn(v);
    const unsigned short l = f32_to_bf16_rn(v - bf16_to_f32(h));
    wpk[(size_t)r * kC + c] = (short)h;
    wpk[(size_t)kO * kC + (size_t)r * kC + c] = (short)l;
  }
}

// ---------------- pack x (one batch): fp32 [c][l] -> bf16 hi/lo [l][c] ----------------
__global__ __launch_bounds__(256) void pack_x(
    const float* __restrict__ x, short* __restrict__ xpk, int b) {
  __shared__ float sT[64][65];
  const int l0 = blockIdx.x * 64;
  const int c0 = blockIdx.y * 64;
  const int t = threadIdx.x;
  const float* xb = x + (size_t)b * kC * kL;
#pragma unroll
  for (int p = 0; p < 4; ++p) {
    const int ch = p * 256 + t;
    const int c = ch >> 4, l4 = (ch & 15) * 4;
    float4 v = *(const float4*)(xb + (size_t)(c0 + c) * kL + l0 + l4);
    sT[c][l4 + 0] = v.x; sT[c][l4 + 1] = v.y; sT[c][l4 + 2] = v.z; sT[c][l4 + 3] = v.w;
  }
  __syncthreads();
#pragma unroll
  for (int p = 0; p < 2; ++p) {
    const int ch = p * 256 + t;
    const int l = ch >> 3, cg = ch & 7;
    short hi[8], lo[8];
#pragma unroll
    for (int j = 0; j < 8; ++j) {
      const float v = sT[cg * 8 + j][l];
      const unsigned short h = f32_to_bf16_rn(v);
      hi[j] = (short)h;
      lo[j] = (short)f32_to_bf16_rn(v - bf16_to_f32(h));
    }
    short* dh = xpk + (size_t)(l0 + l) * kC + c0 + cg * 8;
    *(bf16x8*)dh = *(bf16x8*)hi;
    *(bf16x8*)(dh + (size_t)kL * kC) = *(bf16x8*)lo;
  }
}

// ---------------- projection GEMM via bf16 MFMA, split precision ----------------
__global__ __launch_bounds__(256, 2) void proj_mfma(
    const short* __restrict__ xpk, const short* __restrict__ wpk,
    const float* __restrict__ ball, float* __restrict__ qkv, int b) {
  __shared__ short A_h[128 * 64];
  __shared__ short A_l[128 * 64];
  __shared__ short B_h[128 * 64];
  __shared__ short B_l[128 * 64];
  const int mt = blockIdx.x;          // 0..4
  const int n0 = blockIdx.y * 128;
  const int m0 = mt * 128;
  const bool qk = (mt == 0);
  const int t = threadIdx.x;
  const int wid = t >> 6, lane = t & 63;
  const int wr = wid >> 1, wc = wid & 1;
  const int lr = lane & 15, lg = lane >> 4;

  f32x4 acc[4][4];
#pragma unroll
  for (int i = 0; i < 4; ++i)
#pragma unroll
    for (int j = 0; j < 4; ++j) acc[i][j] = (f32x4)(0.f);

  for (int kt = 0; kt < 8; ++kt) {
    const int k0 = kt * 64;
#pragma unroll
    for (int p = 0; p < 4; ++p) {
      const int ch = p * 256 + t;
      const int row = ch >> 3, kg = ch & 7;
      const short* src = wpk + (size_t)(m0 + row) * kC + k0 + kg * 8;
      const int off = row * 64 + ((kg ^ (row & 7)) << 3);
      *(bf16x8*)&A_h[off] = *(const bf16x8*)src;
      *(bf16x8*)&A_l[off] = *(const bf16x8*)(src + (size_t)kO * kC);
    }
#pragma unroll
    for (int p = 0; p < 4; ++p) {
      const int ch = p * 256 + t;
      const int row = ch >> 3, kg = ch & 7;
      const short* src = xpk + (size_t)(n0 + row) * kC + k0 + kg * 8;
      const int off = row * 64 + ((kg ^ (row & 7)) << 3);
      *(bf16x8*)&B_h[off] = *(const bf16x8*)src;
      if (qk) *(bf16x8*)&B_l[off] = *(const bf16x8*)(src + (size_t)kL * kC);
    }
    __syncthreads();
#pragma unroll
    for (int ks = 0; ks < 2; ++ks) {
      bf16x8 ah[4], al[4], bh[4], bl[4];
#pragma unroll
      for (int mf = 0; mf < 4; ++mf) {
        const int row = wr * 64 + mf * 16 + lr;
        const int kg = ks * 4 + lg;
        const int off = row * 64 + ((kg ^ (row & 7)) << 3);
        ah[mf] = *(const bf16x8*)&A_h[off];
        al[mf] = *(const bf16x8*)&A_l[off];
      }
#pragma unroll
      for (int nf = 0; nf < 4; ++nf) {
        const int row = wc * 64 + nf * 16 + lr;
        const int kg = ks * 4 + lg;
        const int off = row * 64 + ((kg ^ (row & 7)) << 3);
        bh[nf] = *(const bf16x8*)&B_h[off];
        if (qk) bl[nf] = *(const bf16x8*)&B_l[off];
      }
#pragma unroll
      for (int mf = 0; mf < 4; ++mf)
#pragma unroll
        for (int nf = 0; nf < 4; ++nf) {
          acc[mf][nf] = __builtin_amdgcn_mfma_f32_16x16x32_bf16(
              ah[mf], bh[nf], acc[mf][nf], 0, 0, 0);
          acc[mf][nf] = __builtin_amdgcn_mfma_f32_16x16x32_bf16(
              al[mf], bh[nf], acc[mf][nf], 0, 0, 0);
          if (qk)
            acc[mf][nf] = __builtin_amdgcn_mfma_f32_16x16x32_bf16(
                ah[mf], bl[nf], acc[mf][nf], 0, 0, 0);
        }
    }
    __syncthreads();
  }
#pragma unroll
  for (int mf = 0; mf < 4; ++mf) {
#pragma unroll
    for (int r = 0; r < 4; ++r) {
      const int m = m0 + wr * 64 + mf * 16 + lg * 4 + r;
      const float bias = ball[m];
      float* dst = qkv + ((size_t)b * kO + m) * kL + n0 + wc * 64;
#pragma unroll
      for (int nf = 0; nf < 4; ++nf) {
        dst[nf * 16 + lr] = acc[mf][nf][r] + bias;
      }
    }
  }
}

// ---------------- e_row ----------------
__global__ __launch_bounds__(256) void erow_kernel(
    const float* __restrict__ qkv, float* __restrict__ e) {
  __shared__ float sQ[32][128];
  __shared__ float sK[32][128];
  const int bh = blockIdx.x;
  const int b = bh >> 7, h = bh & 127;
  const int t = threadIdx.x;
  const int tx = t & 15, ty = t >> 4;
  float acc[8][8];
#pragma unroll
  for (int i = 0; i < 8; ++i)
#pragma unroll
    for (int j = 0; j < 8; ++j) acc[i][j] = 0.f;

  for (int k0 = 0; k0 < kCQK; k0 += 32) {
#pragma unroll
    for (int p = 0; p < 4; ++p) {
      const int idx = p * 256 + t;
      const int cc = idx >> 5, w4 = (idx & 31) * 4;
      const size_t base = ((size_t)b * kO + k0 + cc) * kL + h * kW + w4;
      *(float4*)&sQ[cc][w4] = *(const float4*)(qkv + base);
      *(float4*)&sK[cc][w4] = *(const float4*)(qkv + base + (size_t)64 * kL);
    }
    __syncthreads();
#pragma unroll
    for (int kk = 0; kk < 32; ++kk) {
      float a[8], bb[8];
      *(float4*)(a + 0) = *(const float4*)&sQ[kk][ty * 8];
      *(float4*)(a + 4) = *(const float4*)&sQ[kk][ty * 8 + 4];
      *(float4*)(bb + 0) = *(const float4*)&sK[kk][tx * 8];
      *(float4*)(bb + 4) = *(const float4*)&sK[kk][tx * 8 + 4];
#pragma unroll
      for (int wi = 0; wi < 8; ++wi)
#pragma unroll
        for (int ii = 0; ii < 8; ++ii) acc[wi][ii] = fmaf(a[wi], bb[ii], acc[wi][ii]);
    }
    __syncthreads();
  }
#pragma unroll
  for (int wi = 0; wi < 8; ++wi) {
    const int w = ty * 8 + wi;
    float* dst = e + (((size_t)b * kH + h) * kW + w) * 256 + tx * 8;
    float4 o0 = {acc[wi][0], acc[wi][1], acc[wi][2], acc[wi][3]};
    float4 o1 = {acc[wi][4], acc[wi][5], acc[wi][6], acc[wi][7]};
    *(float4*)(dst + 0) = o0;
    *(float4*)(dst + 4) = o1;
  }
}

// ---------------- e_col ----------------
__global__ __launch_bounds__(256) void ecol_kernel(
    const float* __restrict__ qkv, float* __restrict__ e) {
  __shared__ float sQ[32][128];
  __shared__ float sK[32][128];
  const int bw = blockIdx.x;
  const int b = bw >> 7, w = bw & 127;
  const int t = threadIdx.x;
  const int tx = t & 15, ty = t >> 4;
  float acc[8][8];
#pragma unroll
  for (int i = 0; i < 8; ++i)
#pragma unroll
    for (int j = 0; j < 8; ++j) acc[i][j] = 0.f;

  for (int k0 = 0; k0 < kCQK; k0 += 32) {
#pragma unroll
    for (int p = 0; p < 16; ++p) {
      const int idx = p * 256 + t;
      const int cc = idx >> 7, hh = idx & 127;
      const size_t base = ((size_t)b * kO + k0 + cc) * kL + hh * kW + w;
      sQ[cc][hh] = qkv[base];
      sK[cc][hh] = qkv[base + (size_t)64 * kL];
    }
    __syncthreads();
#pragma unroll
    for (int kk = 0; kk < 32; ++kk) {
      float a[8], bb[8];
      *(float4*)(a + 0) = *(const float4*)&sQ[kk][ty * 8];
      *(float4*)(a + 4) = *(const float4*)&sQ[kk][ty * 8 + 4];
      *(float4*)(bb + 0) = *(const float4*)&sK[kk][tx * 8];
      *(float4*)(bb + 4) = *(const float4*)&sK[kk][tx * 8 + 4];
#pragma unroll
      for (int hi = 0; hi < 8; ++hi)
#pragma unroll
        for (int ji = 0; ji < 8; ++ji) acc[hi][ji] = fmaf(a[hi], bb[ji], acc[hi][ji]);
    }
    __syncthreads();
  }
  const float NEG_INF = __int_as_float(0xff800000);
#pragma unroll
  for (int hi = 0; hi < 8; ++hi) {
    const int h = ty * 8 + hi;
    float vals[8];
#pragma unroll
    for (int ji = 0; ji < 8; ++ji) {
      const int j = tx * 8 + ji;
      vals[ji] = (j == h) ? NEG_INF : acc[hi][ji];
    }
    float* dst = e + (((size_t)b * kH + h) * kW + w) * 256 + 128 + tx * 8;
    float4 o0 = {vals[0], vals[1], vals[2], vals[3]};
    float4 o1 = {vals[4], vals[5], vals[6], vals[7]};
    *(float4*)(dst + 0) = o0;
    *(float4*)(dst + 4) = o1;
  }
}

// ---------------- softmax; row half -> bf16 arowT, col half -> bf16 afrag ----
__global__ __launch_bounds__(256) void softmax_kernel(
    float* __restrict__ e, float* qkv_base) {
  const int t = threadIdx.x;
  const int wv = t >> 6, lane = t & 63;
  const size_t pix = (size_t)blockIdx.x * 4 + wv;
  float* p = e + pix * 256 + lane * 4;
  float4 v = *(const float4*)p;
  float m = fmaxf(fmaxf(v.x, v.y), fmaxf(v.z, v.w));
#pragma unroll
  for (int off = 32; off > 0; off >>= 1) m = fmaxf(m, __shfl_xor(m, off, 64));
  float e0 = expf(v.x - m), e1 = expf(v.y - m), e2 = expf(v.z - m), e3 = expf(v.w - m);
  float s = e0 + e1 + e2 + e3;
#pragma unroll
  for (int off = 32; off > 0; off >>= 1) s += __shfl_xor(s, off, 64);
  const float inv = 1.0f / s;
  const float o0 = e0 * inv, o1 = e1 * inv, o2 = e2 * inv, o3 = e3 * inv;
  const int b = (int)(pix >> 14);
  const int h = (int)((pix >> 7) & 127);
  const int w = (int)(pix & 127);
  unsigned short* base = (unsigned short*)qkv_base + (size_t)b * kO * kL * 2;
  if (lane < 32) {
    unsigned short* dst = base + AROWT_OFF + (((size_t)h * kW + w) * 128 + lane * 4);
    *(uint2*)dst = make_uint2(pack_bf16x2(o0, o1), pack_bf16x2(o2, o3));
  } else {
    const int s32 = lane - 32;
    const int jb = s32 >> 3;
    const int lg = (s32 >> 1) & 3;
    const int eoff = (s32 & 1) * 4;
    const int hb = h >> 4, hr = h & 15;
    unsigned short* dst = base + (size_t)w * 16384
        + (((size_t)(jb * 8 + hb) * 64 + lg * 16 + hr) * 8 + eoff);
    *(uint2*)dst = make_uint2(pack_bf16x2(o0, o1), pack_bf16x2(o2, o3));
  }
}

// ---------------- vtrans: V fp32 [c][h*128+w] -> vfrag bf16 (MFMA A-frag order) ----
// vfrag[b][w][cb 32][kt 4][lane 64][8]: lane(lr,lg) elem e = v[cb*16+lr][kt*32+lg*8+e][w]
// Lives in the dead e region. Read fully coalesced; write 1KB-contiguous per wave.
__global__ __launch_bounds__(256) void vtrans_kernel(
    const float* __restrict__ qkv, unsigned short* __restrict__ vfrag) {
  __shared__ float sT[16 * VT_SW];   // 69,888 B : [w16][c16][j64] (padded)
  const int cb = blockIdx.x;         // 0..31
  const int wt = blockIdx.y;         // 0..7
  const int b  = blockIdx.z;
  const int t = threadIdx.x;
  const int lane = t & 63, wd = t >> 6;
  const int lr = lane & 15, lg = lane >> 4;
  const float* vb = qkv + ((size_t)b * kO + 128 + cb * 16) * kL + wt * 16;
  unsigned short* vfb = vfrag + (size_t)b * (kL * 128 * 8);  // per-batch 16.7M u16

  for (int half = 0; half < 2; ++half) {
    const int j0 = half * 64;
    // ---- load 16c x 64j x 16w (fully coalesced float4) -> sT[w][c][j] ----
#pragma unroll
    for (int p = 0; p < 16; ++p) {
      const int g = p * 256 + t;          // 0..4095 float4 slots
      const int wq = g & 3;
      const int j = (g >> 2) & 63;
      const int ci = p;                   // g>>8 == p for t<256
      float4 v = *(const float4*)(
          vb + (size_t)ci * kL + (size_t)(j0 + j) * kW + wq * 4);
      float* d = sT + ci * VT_SC + j;
      d[(wq * 4 + 0) * VT_SW] = v.x;
      d[(wq * 4 + 1) * VT_SW] = v.y;
      d[(wq * 4 + 2) * VT_SW] = v.z;
      d[(wq * 4 + 3) * VT_SW] = v.w;
    }
    __syncthreads();
    // ---- emit frags: wave wd handles w = wd*4..+3, ktl 0..1 ----
#pragma unroll
    for (int wi = 0; wi < 4; ++wi) {
      const int w = wd * 4 + wi;
#pragma unroll
      for (int ktl = 0; ktl < 2; ++ktl) {
        const float* s = sT + w * VT_SW + lr * VT_SC + ktl * 32 + lg * 8;
        float a[8];
        *(float4*)(a + 0) = *(const float4*)(s + 0);
        *(float4*)(a + 4) = *(const float4*)(s + 4);
        const int ktg = half * 2 + ktl;
        unsigned short* dst = vfb
            + ((((size_t)(wt * 16 + w) * 32 + cb) * 4 + ktg) * 64 + lane) * 8;
        uint4 o = make_uint4(pack_bf16x2(a[0], a[1]), pack_bf16x2(a[2], a[3]),
                             pack_bf16x2(a[4], a[5]), pack_bf16x2(a[6], a[7]));
        *(uint4*)dst = o;
      }
    }
    __syncthreads();
  }
}

// ---------------- row aggregation via bf16 MFMA ----------------
__global__ __launch_bounds__(256) void rowagg_mfma(
    const float* qkv, float* __restrict__ out) {
  __shared__ short sV[128 * 64];   // [c][i] bf16, swizzled, 16KB
  const int ct = blockIdx.x;       // 0..3
  const int bh = blockIdx.y;
  const int b = bh >> 7, h = bh & 127;
  const int c0 = ct * 128;
  const int t = threadIdx.x;
  const int wid = t >> 6, lane = t & 63;
  const int wr = wid >> 1, wc = wid & 1;
  const int lr = lane & 15, lg = lane >> 4;

  f32x4 acc[4][4];
#pragma unroll
  for (int i = 0; i < 4; ++i)
#pragma unroll
    for (int j = 0; j < 4; ++j) acc[i][j] = (f32x4)(0.f);

  const float* vbase = qkv + ((size_t)b * kO + 128 + c0) * kL + (size_t)h * kW;
  const unsigned short* arbase = (const unsigned short*)qkv
      + (size_t)b * kO * kL * 2 + AROWT_OFF + (size_t)h * kW * 128;

  for (int kt = 0; kt < 2; ++kt) {
    const int i0 = kt * 64;
    {
      const int c = t >> 1;
      const int half = t & 1;
      const float* src = vbase + (size_t)c * kL + i0 + half * 32;
#pragma unroll
      for (int q = 0; q < 4; ++q) {
        const int g = half * 4 + q;
        float4 a0 = *(const float4*)(src + q * 8);
        float4 a1 = *(const float4*)(src + q * 8 + 4);
        unsigned* d = (unsigned*)&sV[c * 64 + ((g ^ (c & 7)) << 3)];
        d[0] = pack_bf16x2(a0.x, a0.y);
        d[1] = pack_bf16x2(a0.z, a0.w);
        d[2] = pack_bf16x2(a1.x, a1.y);
        d[3] = pack_bf16x2(a1.z, a1.w);
      }
    }
    __syncthreads();
#pragma unroll
    for (int ks = 0; ks < 2; ++ks) {
      bf16x8 vfr[4], afr[4];
#pragma unroll
      for (int mf = 0; mf < 4; ++mf) {
        const int row = wr * 64 + mf * 16 + lr;
        const int kg = ks * 4 + lg;
        vfr[mf] = *(const bf16x8*)&sV[row * 64 + ((kg ^ (row & 7)) << 3)];
      }
#pragma unroll
      for (int nf = 0; nf < 4; ++nf) {
        const int w = wc * 64 + nf * 16 + lr;
        afr[nf] = *(const bf16x8*)(arbase + (size_t)w * 128 + i0 + ks * 32 + lg * 8);
      }
#pragma unroll
      for (int mf = 0; mf < 4; ++mf)
#pragma unroll
        for (int nf = 0; nf < 4; ++nf)
          acc[mf][nf] = __builtin_amdgcn_mfma_f32_16x16x32_bf16(
              vfr[mf], afr[nf], acc[mf][nf], 0, 0, 0);
    }
    __syncthreads();
  }
#pragma unroll
  for (int mf = 0; mf < 4; ++mf) {
#pragma unroll
    for (int r = 0; r < 4; ++r) {
      const int c = c0 + wr * 64 + mf * 16 + lg * 4 + r;
      float* dst = out + (((size_t)b * kC + c) * kH + h) * kW + wc * 64;
#pragma unroll
      for (int nf = 0; nf < 4; ++nf) {
        dst[nf * 16 + lr] = acc[mf][nf][r];
      }
    }
  }
}

// ---------------- col aggregation v4: no staging LDS, direct frag loads ----------------
// out[b][c][h][w] += sum_j acol[(h,w)][j] * v[b][c][j][w]
// A-frag = vfrag (fragment-order, contiguous), B-frag = afrag (fragment-order).
// Main loop has NO barriers; LDS used only for the coalesced RMW epilogue.
__global__ __launch_bounds__(1024) void colagg_mfma(
    const float* qkv, const unsigned short* __restrict__ vfrag,
    float* __restrict__ out) {
  __shared__ float sO[64 * SOC];      // 69,888 B (epilogue only)
  const int gx = blockIdx.x;          // ct(8) + 8*ht(2)
  const int ct = gx & 7, ht = gx >> 3;
  const int c0 = ct * 64, h0 = ht * 64;
  const int w0 = blockIdx.y * 16;
  const int b = blockIdx.z;
  const int t = threadIdx.x;          // 0..1023
  const int wv = t >> 6, lane = t & 63;
  const int lr = lane & 15, lg = lane >> 4;
  const int w = w0 + wv;

  f32x4 acc[4][4];   // [mf(c)][nf(h)]
#pragma unroll
  for (int i = 0; i < 4; ++i)
#pragma unroll
    for (int j = 0; j < 4; ++j) acc[i][j] = (f32x4)(0.f);

  const unsigned short* ab = (const unsigned short*)qkv + (size_t)b * kO * kL * 2
      + (size_t)w * 16384;
  const unsigned short* vfb = vfrag + (size_t)b * (kL * 128 * 8)
      + ((size_t)w * 32 + ct * 4) * 2048;

  for (int kt = 0; kt < 4; ++kt) {
    bf16x8 vf[4], af[4];
#pragma unroll
    for (int mf = 0; mf < 4; ++mf)
      vf[mf] = *(const bf16x8*)(vfb + ((size_t)mf * 2048 + kt * 512 + lane * 8));
#pragma unroll
    for (int nf = 0; nf < 4; ++nf)
      af[nf] = *(const bf16x8*)(
          ab + (((size_t)(kt * 8 + ht * 4 + nf) * 64 + lane) * 8));
#pragma unroll
    for (int mf = 0; mf < 4; ++mf)
#pragma unroll
      for (int nf = 0; nf < 4; ++nf)
        acc[mf][nf] = __builtin_amdgcn_mfma_f32_16x16x32_bf16(
            vf[mf], af[nf], acc[mf][nf], 0, 0, 0);
  }

  // ---- epilogue: LDS transpose + fully-coalesced scalar RMW ----
  const int ew = t & 15, ehh = (t >> 4) & 15, ecb = t >> 8;
  for (int nf = 0; nf < 4; ++nf) {
    __syncthreads();
#pragma unroll
    for (int mf = 0; mf < 4; ++mf)
#pragma unroll
      for (int r = 0; r < 4; ++r)
        sO[(mf * 16 + lg * 4 + r) * SOC + lr * SOW + wv] = acc[mf][nf][r];
    __syncthreads();
#pragma unroll
    for (int q = 0; q < 16; ++q) {
      const int c = q * 4 + ecb;
      float* dst = out + (((size_t)b * kC + c0 + c) * kH + h0 + nf * 16 + ehh) * kW
          + w0 + ew;
      *dst += sO[c * SOC + ehh * SOW + ew];
    }
  }
}

extern "C" void kernel_launch(void* const* d_in, const int* in_sizes, int n_in,
                              void* d_out, int out_size, void* d_ws, size_t ws_size,
                              hipStream_t stream) {
  (void)in_sizes; (void)n_in; (void)out_size; (void)ws_size;
  const float* x  = (const float*)d_in[0];
  const float* Wq = (const float*)d_in[1];
  const float* bq = (const float*)d_in[2];
  const float* Wk = (const float*)d_in[3];
  const float* bk = (const float*)d_in[4];
  const float* Wv = (const float*)d_in[5];
  const float* bv = (const float*)d_in[6];
  float* out = (float*)d_out;
  float* ws  = (float*)d_ws;

  short* wpk = (short*)(ws + OFF_WALL);
  float* ball = ws + OFF_BALL;
  float* qkv  = ws + OFF_QKV;
  float* e    = ws + OFF_E;
  short* xpk  = (short*)(ws + OFF_E);           // aliases e (pre-score phase)
  unsigned short* vfrag = (unsigned short*)(ws + OFF_E);  // aliases e (post-softmax)

  pack_w<<<dim3(kO), dim3(256), 0, stream>>>(Wq, bq, Wk, bk, Wv, bv, wpk, ball);
  for (int b = 0; b < kB; ++b) {
    pack_x<<<dim3(kL / 64, kC / 64), dim3(256), 0, stream>>>(x, xpk, b);
    proj_mfma<<<dim3(5, kL / 128), dim3(256), 0, stream>>>(xpk, wpk, ball, qkv, b);
  }
  erow_kernel<<<dim3(kB * kH), dim3(256), 0, stream>>>(qkv, e);
  ecol_kernel<<<dim3(kB * kW), dim3(256), 0, stream>>>(qkv, e);
  softmax_kernel<<<dim3(kB * kH * kW / 4), dim3(256), 0, stream>>>(e, qkv);
  vtrans_kernel<<<dim3(32, 8, kB), dim3(256), 0, stream>>>(qkv, vfrag);
  rowagg_mfma<<<dim3(4, kB * kH), dim3(256), 0, stream>>>(qkv, out);
  colagg_mfma<<<dim3(16, kW / 16, kB), dim3(1024), 0, stream>>>(qkv, vfrag, out);
}

// Round 9
// 540.397 us; speedup vs baseline: 1.5571x; 1.0700x over previous
//
#include <hip/hip_runtime.h>
#include <hip/hip_bf16.h>

namespace {
constexpr int kB = 4;
constexpr int kC = 512;
constexpr int kH = 128;
constexpr int kW = 128;
constexpr int kCQK = 64;
constexpr int kL = kH * kW;   // 16384
constexpr int kO = 640;       // rows: [0,64)=Wq, [64,128)=Wk, [128,640)=Wv

// workspace layout (float offsets)
constexpr size_t OFF_WALL = 0;                          // wpk: 640*512*2 bf16
constexpr size_t OFF_BALL = (size_t)kO * kC;            // 640
constexpr size_t OFF_QKV  = OFF_BALL + kO;              // B*640*L fp32
constexpr size_t OFF_E    = OFF_QKV + (size_t)kB * kO * kL;  // B*H*W*256 fp32
constexpr size_t WS_FLOATS = OFF_E + (size_t)kB * kH * kW * 256;
// q/k region of qkv (first 128 rows/batch = 8.4MB/b) lifecycle:
//   proj writes qkb bf16 planes (u16 offsets): qh@0, ql@1M, kh@2M, kl@3M
//   escore reads qkb; then softmax overwrites with afrag[0,2M) + arowT[2M,4M)
// e region (67MB) lifecycle: xpk (pre-proj) -> scores fp32 -> vfrag bf16

typedef __attribute__((ext_vector_type(8))) short bf16x8;
typedef __attribute__((ext_vector_type(4))) float f32x4;

__device__ __forceinline__ unsigned short f32_to_bf16_rn(float f) {
  unsigned u = __float_as_uint(f);
  unsigned r = (u + 0x7FFFu + ((u >> 16) & 1u)) >> 16;
  return (unsigned short)r;
}
__device__ __forceinline__ float bf16_to_f32(unsigned short h) {
  return __uint_as_float(((unsigned)h) << 16);
}
__device__ __forceinline__ unsigned pack_bf16x2(float a, float b) {
  return (unsigned)f32_to_bf16_rn(a) | ((unsigned)f32_to_bf16_rn(b) << 16);
}
// colagg epilogue sO strides (f32 units)
constexpr int SOW = 17;
constexpr int SOC = 16 * SOW + 1;   // 273
constexpr size_t AROWT_OFF = 2097152;   // u16 offset within q/k region
// qkb plane offsets (u16, within batch q/k region)
constexpr size_t QH_OFF = 0;
constexpr size_t QL_OFF = 1048576;
constexpr size_t KH_OFF = 2097152;
constexpr size_t KL_OFF = 3145728;
// vtrans LDS strides (f32 units)
constexpr int VT_SC = 68;
constexpr int VT_SW = 16 * VT_SC + 4; // 1092
}

// ---------------- pack W/bias into bf16 hi/lo planes [640][512] ----------------
__global__ __launch_bounds__(256) void pack_w(
    const float* __restrict__ Wq, const float* __restrict__ bq,
    const float* __restrict__ Wk, const float* __restrict__ bk,
    const float* __restrict__ Wv, const float* __restrict__ bv,
    short* __restrict__ wpk, float* __restrict__ ball) {
  const int r = blockIdx.x;      // 0..639
  const int t = threadIdx.x;     // 256
  const float* src;
  if (r < 64) {
    src = Wq + (size_t)r * kC;
    if (t == 0) ball[r] = bq[r];
  } else if (r < 128) {
    src = Wk + (size_t)(r - 64) * kC;
    if (t == 0) ball[r] = bk[r - 64];
  } else {
    src = Wv + (size_t)(r - 128) * kC;
    if (t == 0) ball[r] = bv[r - 128];
  }
#pragma unroll
  for (int p = 0; p < 2; ++p) {
    const int c = p * 256 + t;
    const float v = src[c];
    const unsigned short h = f32_to_bf16_rn(v);
    const unsigned short l = f32_to_bf16_rn(v - bf16_to_f32(h));
    wpk[(size_t)r * kC + c] = (short)h;
    wpk[(size_t)kO * kC + (size_t)r * kC + c] = (short)l;
  }
}

// ---------------- pack x (one batch): fp32 [c][l] -> bf16 hi/lo [l][c] ----------------
__global__ __launch_bounds__(256) void pack_x(
    const float* __restrict__ x, short* __restrict__ xpk, int b) {
  __shared__ float sT[64][65];
  const int l0 = blockIdx.x * 64;
  const int c0 = blockIdx.y * 64;
  const int t = threadIdx.x;
  const float* xb = x + (size_t)b * kC * kL;
#pragma unroll
  for (int p = 0; p < 4; ++p) {
    const int ch = p * 256 + t;
    const int c = ch >> 4, l4 = (ch & 15) * 4;
    float4 v = *(const float4*)(xb + (size_t)(c0 + c) * kL + l0 + l4);
    sT[c][l4 + 0] = v.x; sT[c][l4 + 1] = v.y; sT[c][l4 + 2] = v.z; sT[c][l4 + 3] = v.w;
  }
  __syncthreads();
#pragma unroll
  for (int p = 0; p < 2; ++p) {
    const int ch = p * 256 + t;
    const int l = ch >> 3, cg = ch & 7;
    short hi[8], lo[8];
#pragma unroll
    for (int j = 0; j < 8; ++j) {
      const float v = sT[cg * 8 + j][l];
      const unsigned short h = f32_to_bf16_rn(v);
      hi[j] = (short)h;
      lo[j] = (short)f32_to_bf16_rn(v - bf16_to_f32(h));
    }
    short* dh = xpk + (size_t)(l0 + l) * kC + c0 + cg * 8;
    *(bf16x8*)dh = *(bf16x8*)hi;
    *(bf16x8*)(dh + (size_t)kL * kC) = *(bf16x8*)lo;
  }
}

// ---------------- projection GEMM via bf16 MFMA, split precision ----------------
// qk tile (mt==0) writes q,k as bf16 hi/lo planes [h][w][c] (qkb); v tiles fp32.
__global__ __launch_bounds__(256, 2) void proj_mfma(
    const short* __restrict__ xpk, const short* __restrict__ wpk,
    const float* __restrict__ ball, float* __restrict__ qkv, int b) {
  __shared__ short A_h[128 * 64];
  __shared__ short A_l[128 * 64];
  __shared__ short B_h[128 * 64];
  __shared__ short B_l[128 * 64];
  const int mt = blockIdx.x;          // 0..4
  const int n0 = blockIdx.y * 128;
  const int m0 = mt * 128;
  const bool qk = (mt == 0);
  const int t = threadIdx.x;
  const int wid = t >> 6, lane = t & 63;
  const int wr = wid >> 1, wc = wid & 1;
  const int lr = lane & 15, lg = lane >> 4;

  f32x4 acc[4][4];
#pragma unroll
  for (int i = 0; i < 4; ++i)
#pragma unroll
    for (int j = 0; j < 4; ++j) acc[i][j] = (f32x4)(0.f);

  for (int kt = 0; kt < 8; ++kt) {
    const int k0 = kt * 64;
#pragma unroll
    for (int p = 0; p < 4; ++p) {
      const int ch = p * 256 + t;
      const int row = ch >> 3, kg = ch & 7;
      const short* src = wpk + (size_t)(m0 + row) * kC + k0 + kg * 8;
      const int off = row * 64 + ((kg ^ (row & 7)) << 3);
      *(bf16x8*)&A_h[off] = *(const bf16x8*)src;
      *(bf16x8*)&A_l[off] = *(const bf16x8*)(src + (size_t)kO * kC);
    }
#pragma unroll
    for (int p = 0; p < 4; ++p) {
      const int ch = p * 256 + t;
      const int row = ch >> 3, kg = ch & 7;
      const short* src = xpk + (size_t)(n0 + row) * kC + k0 + kg * 8;
      const int off = row * 64 + ((kg ^ (row & 7)) << 3);
      *(bf16x8*)&B_h[off] = *(const bf16x8*)src;
      if (qk) *(bf16x8*)&B_l[off] = *(const bf16x8*)(src + (size_t)kL * kC);
    }
    __syncthreads();
#pragma unroll
    for (int ks = 0; ks < 2; ++ks) {
      bf16x8 ah[4], al[4], bh[4], bl[4];
#pragma unroll
      for (int mf = 0; mf < 4; ++mf) {
        const int row = wr * 64 + mf * 16 + lr;
        const int kg = ks * 4 + lg;
        const int off = row * 64 + ((kg ^ (row & 7)) << 3);
        ah[mf] = *(const bf16x8*)&A_h[off];
        al[mf] = *(const bf16x8*)&A_l[off];
      }
#pragma unroll
      for (int nf = 0; nf < 4; ++nf) {
        const int row = wc * 64 + nf * 16 + lr;
        const int kg = ks * 4 + lg;
        const int off = row * 64 + ((kg ^ (row & 7)) << 3);
        bh[nf] = *(const bf16x8*)&B_h[off];
        if (qk) bl[nf] = *(const bf16x8*)&B_l[off];
      }
#pragma unroll
      for (int mf = 0; mf < 4; ++mf)
#pragma unroll
        for (int nf = 0; nf < 4; ++nf) {
          acc[mf][nf] = __builtin_amdgcn_mfma_f32_16x16x32_bf16(
              ah[mf], bh[nf], acc[mf][nf], 0, 0, 0);
          acc[mf][nf] = __builtin_amdgcn_mfma_f32_16x16x32_bf16(
              al[mf], bh[nf], acc[mf][nf], 0, 0, 0);
          if (qk)
            acc[mf][nf] = __builtin_amdgcn_mfma_f32_16x16x32_bf16(
                ah[mf], bl[nf], acc[mf][nf], 0, 0, 0);
        }
    }
    __syncthreads();
  }
  if (qk) {
    // write qkb: plane = (wr? k : q), [pixel l][c], hi + lo
    unsigned short* qw = (unsigned short*)qkv + (size_t)b * kO * kL * 2
        + (wr ? KH_OFF : QH_OFF);
#pragma unroll
    for (int mf = 0; mf < 4; ++mf) {
      const int c0 = mf * 16 + lg * 4;
#pragma unroll
      for (int nf = 0; nf < 4; ++nf) {
        const int l = n0 + wc * 64 + nf * 16 + lr;
        unsigned short hi4[4], lo4[4];
#pragma unroll
        for (int r = 0; r < 4; ++r) {
          const float val = acc[mf][nf][r] + ball[wr * 64 + c0 + r];
          const unsigned short h = f32_to_bf16_rn(val);
          hi4[r] = h;
          lo4[r] = f32_to_bf16_rn(val - bf16_to_f32(h));
        }
        unsigned short* d = qw + ((size_t)l * 64 + c0);
        *(uint2*)d = *(uint2*)hi4;
        *(uint2*)(d + QL_OFF) = *(uint2*)lo4;   // lo plane is +1M u16 for both q,k
      }
    }
  } else {
#pragma unroll
    for (int mf = 0; mf < 4; ++mf) {
#pragma unroll
      for (int r = 0; r < 4; ++r) {
        const int m = m0 + wr * 64 + mf * 16 + lg * 4 + r;
        const float bias = ball[m];
        float* dst = qkv + ((size_t)b * kO + m) * kL + n0 + wc * 64;
#pragma unroll
        for (int nf = 0; nf < 4; ++nf) {
          dst[nf * 16 + lr] = acc[mf][nf][r] + bias;
        }
      }
    }
  }
}

// ---------------- scores via MFMA, 3-pass split precision ----------------
// ROW (COL=0): per (b,h): e[pix(h,w)][i]     = sum_c q[w][c]*k[i][c]
// COL (COL=1): per (b,w): e[pix(h,w)][128+j] = sum_c q[h][c]*k[j][c], diag -inf
// D[row=i/j][col=w/h]; A=k rows, B=q rows; direct global frag loads, no LDS.
template <int COL>
__global__ __launch_bounds__(256) void escore_mfma(
    const float* qkv, float* __restrict__ e) {
  const int bi = blockIdx.x;           // b*128 + idx
  const int b = bi >> 7, idx = bi & 127;
  const int t = threadIdx.x;
  const int wid = t >> 6, lane = t & 63;
  const int wj = wid >> 1, wh = wid & 1;
  const int lr = lane & 15, lg = lane >> 4;

  const unsigned short* qkb = (const unsigned short*)qkv + (size_t)b * kO * kL * 2;
  const size_t baseoff = COL ? (size_t)idx * 64 : (size_t)idx * 8192;
  const int rstride = COL ? 8192 : 64;

  f32x4 acc[4][4];
#pragma unroll
  for (int i = 0; i < 4; ++i)
#pragma unroll
    for (int j = 0; j < 4; ++j) acc[i][j] = (f32x4)(0.f);

#pragma unroll
  for (int ks = 0; ks < 2; ++ks) {
    bf16x8 ah[4], al[4], bh[4], bl[4];
#pragma unroll
    for (int mf = 0; mf < 4; ++mf) {
      const size_t ro = baseoff + (size_t)(wj * 64 + mf * 16 + lr) * rstride
          + ks * 32 + lg * 8;
      ah[mf] = *(const bf16x8*)(qkb + KH_OFF + ro);
      al[mf] = *(const bf16x8*)(qkb + KL_OFF + ro);
    }
#pragma unroll
    for (int nf = 0; nf < 4; ++nf) {
      const size_t ro = baseoff + (size_t)(wh * 64 + nf * 16 + lr) * rstride
          + ks * 32 + lg * 8;
      bh[nf] = *(const bf16x8*)(qkb + QH_OFF + ro);
      bl[nf] = *(const bf16x8*)(qkb + QL_OFF + ro);
    }
#pragma unroll
    for (int mf = 0; mf < 4; ++mf)
#pragma unroll
      for (int nf = 0; nf < 4; ++nf) {
        acc[mf][nf] = __builtin_amdgcn_mfma_f32_16x16x32_bf16(
            ah[mf], bh[nf], acc[mf][nf], 0, 0, 0);
        acc[mf][nf] = __builtin_amdgcn_mfma_f32_16x16x32_bf16(
            ah[mf], bl[nf], acc[mf][nf], 0, 0, 0);
        acc[mf][nf] = __builtin_amdgcn_mfma_f32_16x16x32_bf16(
            al[mf], bh[nf], acc[mf][nf], 0, 0, 0);
      }
  }
  const float NEG_INF = __int_as_float(0xff800000);
#pragma unroll
  for (int mf = 0; mf < 4; ++mf) {
    const int row0 = wj * 64 + mf * 16 + lg * 4;     // i or j
#pragma unroll
    for (int nf = 0; nf < 4; ++nf) {
      const int cl = wh * 64 + nf * 16 + lr;          // w or h
      float o[4];
#pragma unroll
      for (int r = 0; r < 4; ++r) {
        float v = acc[mf][nf][r];
        if (COL && (row0 + r == cl)) v = NEG_INF;
        o[r] = v;
      }
      float* dst;
      if (COL)
        dst = e + (((size_t)b * kH + cl) * kW + idx) * 256 + 128 + row0;
      else
        dst = e + (((size_t)b * kH + idx) * kW + cl) * 256 + row0;
      *(float4*)dst = *(const float4*)o;
    }
  }
}

// ---------------- softmax; row half -> bf16 arowT, col half -> bf16 afrag ----
__global__ __launch_bounds__(256) void softmax_kernel(
    float* __restrict__ e, float* qkv_base) {
  const int t = threadIdx.x;
  const int wv = t >> 6, lane = t & 63;
  const size_t pix = (size_t)blockIdx.x * 4 + wv;
  float* p = e + pix * 256 + lane * 4;
  float4 v = *(const float4*)p;
  float m = fmaxf(fmaxf(v.x, v.y), fmaxf(v.z, v.w));
#pragma unroll
  for (int off = 32; off > 0; off >>= 1) m = fmaxf(m, __shfl_xor(m, off, 64));
  float e0 = expf(v.x - m), e1 = expf(v.y - m), e2 = expf(v.z - m), e3 = expf(v.w - m);
  float s = e0 + e1 + e2 + e3;
#pragma unroll
  for (int off = 32; off > 0; off >>= 1) s += __shfl_xor(s, off, 64);
  const float inv = 1.0f / s;
  const float o0 = e0 * inv, o1 = e1 * inv, o2 = e2 * inv, o3 = e3 * inv;
  const int b = (int)(pix >> 14);
  const int h = (int)((pix >> 7) & 127);
  const int w = (int)(pix & 127);
  unsigned short* base = (unsigned short*)qkv_base + (size_t)b * kO * kL * 2;
  if (lane < 32) {
    unsigned short* dst = base + AROWT_OFF + (((size_t)h * kW + w) * 128 + lane * 4);
    *(uint2*)dst = make_uint2(pack_bf16x2(o0, o1), pack_bf16x2(o2, o3));
  } else {
    const int s32 = lane - 32;
    const int jb = s32 >> 3;
    const int lg = (s32 >> 1) & 3;
    const int eoff = (s32 & 1) * 4;
    const int hb = h >> 4, hr = h & 15;
    unsigned short* dst = base + (size_t)w * 16384
        + (((size_t)(jb * 8 + hb) * 64 + lg * 16 + hr) * 8 + eoff);
    *(uint2*)dst = make_uint2(pack_bf16x2(o0, o1), pack_bf16x2(o2, o3));
  }
}

// ---------------- vtrans: V fp32 -> vfrag bf16 (MFMA A-frag order) ----------------
__global__ __launch_bounds__(256) void vtrans_kernel(
    const float* __restrict__ qkv, unsigned short* __restrict__ vfrag) {
  __shared__ float sT[16 * VT_SW];   // 69,888 B : [w16][c16][j64]
  const int cb = blockIdx.x;         // 0..31
  const int wt = blockIdx.y;         // 0..7
  const int b  = blockIdx.z;
  const int t = threadIdx.x;
  const int lane = t & 63, wd = t >> 6;
  const int lr = lane & 15, lg = lane >> 4;
  const float* vb = qkv + ((size_t)b * kO + 128 + cb * 16) * kL + wt * 16;
  unsigned short* vfb = vfrag + (size_t)b * (kL * 128 * 8);

  for (int half = 0; half < 2; ++half) {
    const int j0 = half * 64;
#pragma unroll
    for (int p = 0; p < 16; ++p) {
      const int g = p * 256 + t;
      const int wq = g & 3;
      const int j = (g >> 2) & 63;
      const int ci = p;
      float4 v = *(const float4*)(
          vb + (size_t)ci * kL + (size_t)(j0 + j) * kW + wq * 4);
      float* d = sT + ci * VT_SC + j;
      d[(wq * 4 + 0) * VT_SW] = v.x;
      d[(wq * 4 + 1) * VT_SW] = v.y;
      d[(wq * 4 + 2) * VT_SW] = v.z;
      d[(wq * 4 + 3) * VT_SW] = v.w;
    }
    __syncthreads();
#pragma unroll
    for (int wi = 0; wi < 4; ++wi) {
      const int w = wd * 4 + wi;
#pragma unroll
      for (int ktl = 0; ktl < 2; ++ktl) {
        const float* s = sT + w * VT_SW + lr * VT_SC + ktl * 32 + lg * 8;
        float a[8];
        *(float4*)(a + 0) = *(const float4*)(s + 0);
        *(float4*)(a + 4) = *(const float4*)(s + 4);
        const int ktg = half * 2 + ktl;
        unsigned short* dst = vfb
            + ((((size_t)(wt * 16 + w) * 32 + cb) * 4 + ktg) * 64 + lane) * 8;
        uint4 o = make_uint4(pack_bf16x2(a[0], a[1]), pack_bf16x2(a[2], a[3]),
                             pack_bf16x2(a[4], a[5]), pack_bf16x2(a[6], a[7]));
        *(uint4*)dst = o;
      }
    }
    __syncthreads();
  }
}

// ---------------- row aggregation via bf16 MFMA ----------------
__global__ __launch_bounds__(256) void rowagg_mfma(
    const float* qkv, float* __restrict__ out) {
  __shared__ short sV[128 * 64];
  const int ct = blockIdx.x;       // 0..3
  const int bh = blockIdx.y;
  const int b = bh >> 7, h = bh & 127;
  const int c0 = ct * 128;
  const int t = threadIdx.x;
  const int wid = t >> 6, lane = t & 63;
  const int wr = wid >> 1, wc = wid & 1;
  const int lr = lane & 15, lg = lane >> 4;

  f32x4 acc[4][4];
#pragma unroll
  for (int i = 0; i < 4; ++i)
#pragma unroll
    for (int j = 0; j < 4; ++j) acc[i][j] = (f32x4)(0.f);

  const float* vbase = qkv + ((size_t)b * kO + 128 + c0) * kL + (size_t)h * kW;
  const unsigned short* arbase = (const unsigned short*)qkv
      + (size_t)b * kO * kL * 2 + AROWT_OFF + (size_t)h * kW * 128;

  for (int kt = 0; kt < 2; ++kt) {
    const int i0 = kt * 64;
    {
      const int c = t >> 1;
      const int half = t & 1;
      const float* src = vbase + (size_t)c * kL + i0 + half * 32;
#pragma unroll
      for (int q = 0; q < 4; ++q) {
        const int g = half * 4 + q;
        float4 a0 = *(const float4*)(src + q * 8);
        float4 a1 = *(const float4*)(src + q * 8 + 4);
        unsigned* d = (unsigned*)&sV[c * 64 + ((g ^ (c & 7)) << 3)];
        d[0] = pack_bf16x2(a0.x, a0.y);
        d[1] = pack_bf16x2(a0.z, a0.w);
        d[2] = pack_bf16x2(a1.x, a1.y);
        d[3] = pack_bf16x2(a1.z, a1.w);
      }
    }
    __syncthreads();
#pragma unroll
    for (int ks = 0; ks < 2; ++ks) {
      bf16x8 vfr[4], afr[4];
#pragma unroll
      for (int mf = 0; mf < 4; ++mf) {
        const int row = wr * 64 + mf * 16 + lr;
        const int kg = ks * 4 + lg;
        vfr[mf] = *(const bf16x8*)&sV[row * 64 + ((kg ^ (row & 7)) << 3)];
      }
#pragma unroll
      for (int nf = 0; nf < 4; ++nf) {
        const int w = wc * 64 + nf * 16 + lr;
        afr[nf] = *(const bf16x8*)(arbase + (size_t)w * 128 + i0 + ks * 32 + lg * 8);
      }
#pragma unroll
      for (int mf = 0; mf < 4; ++mf)
#pragma unroll
        for (int nf = 0; nf < 4; ++nf)
          acc[mf][nf] = __builtin_amdgcn_mfma_f32_16x16x32_bf16(
              vfr[mf], afr[nf], acc[mf][nf], 0, 0, 0);
    }
    __syncthreads();
  }
#pragma unroll
  for (int mf = 0; mf < 4; ++mf) {
#pragma unroll
    for (int r = 0; r < 4; ++r) {
      const int c = c0 + wr * 64 + mf * 16 + lg * 4 + r;
      float* dst = out + (((size_t)b * kC + c) * kH + h) * kW + wc * 64;
#pragma unroll
      for (int nf = 0; nf < 4; ++nf) {
        dst[nf * 16 + lr] = acc[mf][nf][r];
      }
    }
  }
}

// ---------------- col aggregation: no staging LDS, direct frag loads ----------------
__global__ __launch_bounds__(1024) void colagg_mfma(
    const float* qkv, const unsigned short* __restrict__ vfrag,
    float* __restrict__ out) {
  __shared__ float sO[64 * SOC];      // epilogue only
  const int gx = blockIdx.x;          // ct(8) + 8*ht(2)
  const int ct = gx & 7, ht = gx >> 3;
  const int c0 = ct * 64, h0 = ht * 64;
  const int w0 = blockIdx.y * 16;
  const int b = blockIdx.z;
  const int t = threadIdx.x;          // 0..1023
  const int wv = t >> 6, lane = t & 63;
  const int lr = lane & 15, lg = lane >> 4;
  const int w = w0 + wv;

  f32x4 acc[4][4];
#pragma unroll
  for (int i = 0; i < 4; ++i)
#pragma unroll
    for (int j = 0; j < 4; ++j) acc[i][j] = (f32x4)(0.f);

  const unsigned short* ab = (const unsigned short*)qkv + (size_t)b * kO * kL * 2
      + (size_t)w * 16384;
  const unsigned short* vfb = vfrag + (size_t)b * (kL * 128 * 8)
      + ((size_t)w * 32 + ct * 4) * 2048;

  for (int kt = 0; kt < 4; ++kt) {
    bf16x8 vf[4], af[4];
#pragma unroll
    for (int mf = 0; mf < 4; ++mf)
      vf[mf] = *(const bf16x8*)(vfb + ((size_t)mf * 2048 + kt * 512 + lane * 8));
#pragma unroll
    for (int nf = 0; nf < 4; ++nf)
      af[nf] = *(const bf16x8*)(
          ab + (((size_t)(kt * 8 + ht * 4 + nf) * 64 + lane) * 8));
#pragma unroll
    for (int mf = 0; mf < 4; ++mf)
#pragma unroll
      for (int nf = 0; nf < 4; ++nf)
        acc[mf][nf] = __builtin_amdgcn_mfma_f32_16x16x32_bf16(
            vf[mf], af[nf], acc[mf][nf], 0, 0, 0);
  }

  const int ew = t & 15, ehh = (t >> 4) & 15, ecb = t >> 8;
  for (int nf = 0; nf < 4; ++nf) {
    __syncthreads();
#pragma unroll
    for (int mf = 0; mf < 4; ++mf)
#pragma unroll
      for (int r = 0; r < 4; ++r)
        sO[(mf * 16 + lg * 4 + r) * SOC + lr * SOW + wv] = acc[mf][nf][r];
    __syncthreads();
#pragma unroll
    for (int q = 0; q < 16; ++q) {
      const int c = q * 4 + ecb;
      float* dst = out + (((size_t)b * kC + c0 + c) * kH + h0 + nf * 16 + ehh) * kW
          + w0 + ew;
      *dst += sO[c * SOC + ehh * SOW + ew];
    }
  }
}

extern "C" void kernel_launch(void* const* d_in, const int* in_sizes, int n_in,
                              void* d_out, int out_size, void* d_ws, size_t ws_size,
                              hipStream_t stream) {
  (void)in_sizes; (void)n_in; (void)out_size; (void)ws_size;
  const float* x  = (const float*)d_in[0];
  const float* Wq = (const float*)d_in[1];
  const float* bq = (const float*)d_in[2];
  const float* Wk = (const float*)d_in[3];
  const float* bk = (const float*)d_in[4];
  const float* Wv = (const float*)d_in[5];
  const float* bv = (const float*)d_in[6];
  float* out = (float*)d_out;
  float* ws  = (float*)d_ws;

  short* wpk = (short*)(ws + OFF_WALL);
  float* ball = ws + OFF_BALL;
  float* qkv  = ws + OFF_QKV;
  float* e    = ws + OFF_E;
  short* xpk  = (short*)(ws + OFF_E);
  unsigned short* vfrag = (unsigned short*)(ws + OFF_E);

  pack_w<<<dim3(kO), dim3(256), 0, stream>>>(Wq, bq, Wk, bk, Wv, bv, wpk, ball);
  for (int b = 0; b < kB; ++b) {
    pack_x<<<dim3(kL / 64, kC / 64), dim3(256), 0, stream>>>(x, xpk, b);
    proj_mfma<<<dim3(5, kL / 128), dim3(256), 0, stream>>>(xpk, wpk, ball, qkv, b);
  }
  escore_mfma<0><<<dim3(kB * kH), dim3(256), 0, stream>>>(qkv, e);
  escore_mfma<1><<<dim3(kB * kW), dim3(256), 0, stream>>>(qkv, e);
  softmax_kernel<<<dim3(kB * kH * kW / 4), dim3(256), 0, stream>>>(e, qkv);
  vtrans_kernel<<<dim3(32, 8, kB), dim3(256), 0, stream>>>(qkv, vfrag);
  rowagg_mfma<<<dim3(4, kB * kH), dim3(256), 0, stream>>>(qkv, out);
  colagg_mfma<<<dim3(16, kW / 16, kB), dim3(1024), 0, stream>>>(qkv, vfrag, out);
}

// Round 10
// 493.717 us; speedup vs baseline: 1.7043x; 1.0945x over previous
//
#include <hip/hip_runtime.h>
#include <hip/hip_bf16.h>

namespace {
constexpr int kB = 4;
constexpr int kC = 512;
constexpr int kH = 128;
constexpr int kW = 128;
constexpr int kCQK = 64;
constexpr int kL = kH * kW;   // 16384
constexpr int kO = 640;       // rows: [0,64)=Wq, [64,128)=Wk, [128,640)=Wv

// workspace layout (float offsets)
constexpr size_t OFF_WALL = 0;                          // wpk: 640*512*2 bf16
constexpr size_t OFF_BALL = (size_t)kO * kC;            // 640
constexpr size_t OFF_QKV  = OFF_BALL + kO;              // B*640*L fp32
constexpr size_t OFF_E    = OFF_QKV + (size_t)kB * kO * kL;  // B*H*W*256 fp32
constexpr size_t WS_FLOATS = OFF_E + (size_t)kB * kH * kW * 256;
// q/k region of qkv (first 128 rows/batch = 8.4MB/b) lifecycle:
//   proj writes qkb bf16 planes (u16 offsets): qh@0, ql@1M, kh@2M, kl@3M
//   escore reads qkb; then softmax overwrites with afrag[0,2M) + arowT[2M,4M)
// e region (67MB) lifecycle: xpk (pre-proj) -> scores fp32 -> vfrag bf16

typedef __attribute__((ext_vector_type(8))) short bf16x8;
typedef __attribute__((ext_vector_type(4))) float f32x4;

__device__ __forceinline__ unsigned short f32_to_bf16_rn(float f) {
  unsigned u = __float_as_uint(f);
  unsigned r = (u + 0x7FFFu + ((u >> 16) & 1u)) >> 16;
  return (unsigned short)r;
}
__device__ __forceinline__ float bf16_to_f32(unsigned short h) {
  return __uint_as_float(((unsigned)h) << 16);
}
__device__ __forceinline__ unsigned pack_bf16x2(float a, float b) {
  return (unsigned)f32_to_bf16_rn(a) | ((unsigned)f32_to_bf16_rn(b) << 16);
}
// colagg epilogue sO strides (f32 units)
constexpr int SOW = 17;
constexpr int SOC = 16 * SOW + 1;   // 273
constexpr size_t AROWT_OFF = 2097152;   // u16 offset within q/k region
// qkb plane offsets (u16, within batch q/k region)
constexpr size_t QH_OFF = 0;
constexpr size_t QL_OFF = 1048576;
constexpr size_t KH_OFF = 2097152;
constexpr size_t KL_OFF = 3145728;
// vtrans LDS strides (f32 units)
constexpr int VT_SC = 68;
constexpr int VT_SW = 16 * VT_SC + 4; // 1092
// vfrag per-batch stride (u16): 128w * 32cb * 4kt * 64lane * 8 = 8.4M
constexpr size_t VFRAG_B = (size_t)kW * 32 * 4 * 64 * 8;
}

// ---------------- pack W/bias into bf16 hi/lo planes [640][512] ----------------
__global__ __launch_bounds__(256) void pack_w(
    const float* __restrict__ Wq, const float* __restrict__ bq,
    const float* __restrict__ Wk, const float* __restrict__ bk,
    const float* __restrict__ Wv, const float* __restrict__ bv,
    short* __restrict__ wpk, float* __restrict__ ball) {
  const int r = blockIdx.x;      // 0..639
  const int t = threadIdx.x;     // 256
  const float* src;
  if (r < 64) {
    src = Wq + (size_t)r * kC;
    if (t == 0) ball[r] = bq[r];
  } else if (r < 128) {
    src = Wk + (size_t)(r - 64) * kC;
    if (t == 0) ball[r] = bk[r - 64];
  } else {
    src = Wv + (size_t)(r - 128) * kC;
    if (t == 0) ball[r] = bv[r - 128];
  }
#pragma unroll
  for (int p = 0; p < 2; ++p) {
    const int c = p * 256 + t;
    const float v = src[c];
    const unsigned short h = f32_to_bf16_rn(v);
    const unsigned short l = f32_to_bf16_rn(v - bf16_to_f32(h));
    wpk[(size_t)r * kC + c] = (short)h;
    wpk[(size_t)kO * kC + (size_t)r * kC + c] = (short)l;
  }
}

// ---------------- pack x (one batch): fp32 [c][l] -> bf16 hi/lo [l][c] ----------------
__global__ __launch_bounds__(256) void pack_x(
    const float* __restrict__ x, short* __restrict__ xpk, int b) {
  __shared__ float sT[64][65];
  const int l0 = blockIdx.x * 64;
  const int c0 = blockIdx.y * 64;
  const int t = threadIdx.x;
  const float* xb = x + (size_t)b * kC * kL;
#pragma unroll
  for (int p = 0; p < 4; ++p) {
    const int ch = p * 256 + t;
    const int c = ch >> 4, l4 = (ch & 15) * 4;
    float4 v = *(const float4*)(xb + (size_t)(c0 + c) * kL + l0 + l4);
    sT[c][l4 + 0] = v.x; sT[c][l4 + 1] = v.y; sT[c][l4 + 2] = v.z; sT[c][l4 + 3] = v.w;
  }
  __syncthreads();
#pragma unroll
  for (int p = 0; p < 2; ++p) {
    const int ch = p * 256 + t;
    const int l = ch >> 3, cg = ch & 7;
    short hi[8], lo[8];
#pragma unroll
    for (int j = 0; j < 8; ++j) {
      const float v = sT[cg * 8 + j][l];
      const unsigned short h = f32_to_bf16_rn(v);
      hi[j] = (short)h;
      lo[j] = (short)f32_to_bf16_rn(v - bf16_to_f32(h));
    }
    short* dh = xpk + (size_t)(l0 + l) * kC + c0 + cg * 8;
    *(bf16x8*)dh = *(bf16x8*)hi;
    *(bf16x8*)(dh + (size_t)kL * kC) = *(bf16x8*)lo;
  }
}

// ---------------- projection GEMM via bf16 MFMA, split precision ----------------
// Staging via global_load_lds (direct-to-LDS, width 16); LDS linear dest with
// pre-swizzled global source (kg = kgp ^ (row&7)) so reads keep the XOR layout.
__global__ __launch_bounds__(256, 2) void proj_mfma(
    const short* __restrict__ xpk, const short* __restrict__ wpk,
    const float* __restrict__ ball, float* __restrict__ qkv, int b) {
  __shared__ short A_h[128 * 64];
  __shared__ short A_l[128 * 64];
  __shared__ short B_h[128 * 64];
  __shared__ short B_l[128 * 64];
  const int mt = blockIdx.x;          // 0..4
  const int n0 = blockIdx.y * 128;
  const int m0 = mt * 128;
  const bool qk = (mt == 0);
  const int t = threadIdx.x;
  const int wid = t >> 6, lane = t & 63;
  const int wr = wid >> 1, wc = wid & 1;
  const int lr = lane & 15, lg = lane >> 4;
  // staging roles (wave-chunk linear dest, swizzled source)
  const int srow8 = lane >> 3;                 // row within 8-row group
  const int skg = (lane & 7) ^ srow8;          // pre-swizzled k-group

  f32x4 acc[4][4];
#pragma unroll
  for (int i = 0; i < 4; ++i)
#pragma unroll
    for (int j = 0; j < 4; ++j) acc[i][j] = (f32x4)(0.f);

  for (int kt = 0; kt < 8; ++kt) {
    const int k0 = kt * 64;
#pragma unroll
    for (int p = 0; p < 4; ++p) {
      const int ck = p * 4 + wid;              // 16 wave-chunks of 1KB
      const int row = ck * 8 + srow8;
      const short* srcA = wpk + (size_t)(m0 + row) * kC + k0 + skg * 8;
      const short* srcB = xpk + (size_t)(n0 + row) * kC + k0 + skg * 8;
      __builtin_amdgcn_global_load_lds(
          (const __attribute__((address_space(1))) void*)srcA,
          (__attribute__((address_space(3))) void*)&A_h[ck * 512], 16, 0, 0);
      __builtin_amdgcn_global_load_lds(
          (const __attribute__((address_space(1))) void*)(srcA + (size_t)kO * kC),
          (__attribute__((address_space(3))) void*)&A_l[ck * 512], 16, 0, 0);
      __builtin_amdgcn_global_load_lds(
          (const __attribute__((address_space(1))) void*)srcB,
          (__attribute__((address_space(3))) void*)&B_h[ck * 512], 16, 0, 0);
      if (qk)
        __builtin_amdgcn_global_load_lds(
            (const __attribute__((address_space(1))) void*)(srcB + (size_t)kL * kC),
            (__attribute__((address_space(3))) void*)&B_l[ck * 512], 16, 0, 0);
    }
    __syncthreads();
#pragma unroll
    for (int ks = 0; ks < 2; ++ks) {
      bf16x8 ah[4], al[4], bh[4], bl[4];
#pragma unroll
      for (int mf = 0; mf < 4; ++mf) {
        const int row = wr * 64 + mf * 16 + lr;
        const int kg = ks * 4 + lg;
        const int off = row * 64 + ((kg ^ (row & 7)) << 3);
        ah[mf] = *(const bf16x8*)&A_h[off];
        al[mf] = *(const bf16x8*)&A_l[off];
      }
#pragma unroll
      for (int nf = 0; nf < 4; ++nf) {
        const int row = wc * 64 + nf * 16 + lr;
        const int kg = ks * 4 + lg;
        const int off = row * 64 + ((kg ^ (row & 7)) << 3);
        bh[nf] = *(const bf16x8*)&B_h[off];
        if (qk) bl[nf] = *(const bf16x8*)&B_l[off];
      }
#pragma unroll
      for (int mf = 0; mf < 4; ++mf)
#pragma unroll
        for (int nf = 0; nf < 4; ++nf) {
          acc[mf][nf] = __builtin_amdgcn_mfma_f32_16x16x32_bf16(
              ah[mf], bh[nf], acc[mf][nf], 0, 0, 0);
          acc[mf][nf] = __builtin_amdgcn_mfma_f32_16x16x32_bf16(
              al[mf], bh[nf], acc[mf][nf], 0, 0, 0);
          if (qk)
            acc[mf][nf] = __builtin_amdgcn_mfma_f32_16x16x32_bf16(
                ah[mf], bl[nf], acc[mf][nf], 0, 0, 0);
        }
    }
    __syncthreads();
  }
  if (qk) {
    unsigned short* qw = (unsigned short*)qkv + (size_t)b * kO * kL * 2
        + (wr ? KH_OFF : QH_OFF);
#pragma unroll
    for (int mf = 0; mf < 4; ++mf) {
      const int c0 = mf * 16 + lg * 4;
#pragma unroll
      for (int nf = 0; nf < 4; ++nf) {
        const int l = n0 + wc * 64 + nf * 16 + lr;
        unsigned short hi4[4], lo4[4];
#pragma unroll
        for (int r = 0; r < 4; ++r) {
          const float val = acc[mf][nf][r] + ball[wr * 64 + c0 + r];
          const unsigned short h = f32_to_bf16_rn(val);
          hi4[r] = h;
          lo4[r] = f32_to_bf16_rn(val - bf16_to_f32(h));
        }
        unsigned short* d = qw + ((size_t)l * 64 + c0);
        *(uint2*)d = *(uint2*)hi4;
        *(uint2*)(d + QL_OFF) = *(uint2*)lo4;
      }
    }
  } else {
#pragma unroll
    for (int mf = 0; mf < 4; ++mf) {
#pragma unroll
      for (int r = 0; r < 4; ++r) {
        const int m = m0 + wr * 64 + mf * 16 + lg * 4 + r;
        const float bias = ball[m];
        float* dst = qkv + ((size_t)b * kO + m) * kL + n0 + wc * 64;
#pragma unroll
        for (int nf = 0; nf < 4; ++nf) {
          dst[nf * 16 + lr] = acc[mf][nf][r] + bias;
        }
      }
    }
  }
}

// ---------------- scores via MFMA, 3-pass split precision ----------------
template <int COL>
__global__ __launch_bounds__(256) void escore_mfma(
    const float* qkv, float* __restrict__ e) {
  const int bi = blockIdx.x;           // b*128 + idx
  const int b = bi >> 7, idx = bi & 127;
  const int t = threadIdx.x;
  const int wid = t >> 6, lane = t & 63;
  const int wj = wid >> 1, wh = wid & 1;
  const int lr = lane & 15, lg = lane >> 4;

  const unsigned short* qkb = (const unsigned short*)qkv + (size_t)b * kO * kL * 2;
  const size_t baseoff = COL ? (size_t)idx * 64 : (size_t)idx * 8192;
  const int rstride = COL ? 8192 : 64;

  f32x4 acc[4][4];
#pragma unroll
  for (int i = 0; i < 4; ++i)
#pragma unroll
    for (int j = 0; j < 4; ++j) acc[i][j] = (f32x4)(0.f);

#pragma unroll
  for (int ks = 0; ks < 2; ++ks) {
    bf16x8 ah[4], al[4], bh[4], bl[4];
#pragma unroll
    for (int mf = 0; mf < 4; ++mf) {
      const size_t ro = baseoff + (size_t)(wj * 64 + mf * 16 + lr) * rstride
          + ks * 32 + lg * 8;
      ah[mf] = *(const bf16x8*)(qkb + KH_OFF + ro);
      al[mf] = *(const bf16x8*)(qkb + KL_OFF + ro);
    }
#pragma unroll
    for (int nf = 0; nf < 4; ++nf) {
      const size_t ro = baseoff + (size_t)(wh * 64 + nf * 16 + lr) * rstride
          + ks * 32 + lg * 8;
      bh[nf] = *(const bf16x8*)(qkb + QH_OFF + ro);
      bl[nf] = *(const bf16x8*)(qkb + QL_OFF + ro);
    }
#pragma unroll
    for (int mf = 0; mf < 4; ++mf)
#pragma unroll
      for (int nf = 0; nf < 4; ++nf) {
        acc[mf][nf] = __builtin_amdgcn_mfma_f32_16x16x32_bf16(
            ah[mf], bh[nf], acc[mf][nf], 0, 0, 0);
        acc[mf][nf] = __builtin_amdgcn_mfma_f32_16x16x32_bf16(
            ah[mf], bl[nf], acc[mf][nf], 0, 0, 0);
        acc[mf][nf] = __builtin_amdgcn_mfma_f32_16x16x32_bf16(
            al[mf], bh[nf], acc[mf][nf], 0, 0, 0);
      }
  }
  const float NEG_INF = __int_as_float(0xff800000);
#pragma unroll
  for (int mf = 0; mf < 4; ++mf) {
    const int row0 = wj * 64 + mf * 16 + lg * 4;     // i or j
#pragma unroll
    for (int nf = 0; nf < 4; ++nf) {
      const int cl = wh * 64 + nf * 16 + lr;          // w or h
      float o[4];
#pragma unroll
      for (int r = 0; r < 4; ++r) {
        float v = acc[mf][nf][r];
        if (COL && (row0 + r == cl)) v = NEG_INF;
        o[r] = v;
      }
      float* dst;
      if (COL)
        dst = e + (((size_t)b * kH + cl) * kW + idx) * 256 + 128 + row0;
      else
        dst = e + (((size_t)b * kH + idx) * kW + cl) * 256 + row0;
      *(float4*)dst = *(const float4*)o;
    }
  }
}

// ---------------- softmax; row half -> bf16 arowT, col half -> bf16 afrag ----
__global__ __launch_bounds__(256) void softmax_kernel(
    float* __restrict__ e, float* qkv_base) {
  const int t = threadIdx.x;
  const int wv = t >> 6, lane = t & 63;
  const size_t pix = (size_t)blockIdx.x * 4 + wv;
  float* p = e + pix * 256 + lane * 4;
  float4 v = *(const float4*)p;
  float m = fmaxf(fmaxf(v.x, v.y), fmaxf(v.z, v.w));
#pragma unroll
  for (int off = 32; off > 0; off >>= 1) m = fmaxf(m, __shfl_xor(m, off, 64));
  float e0 = expf(v.x - m), e1 = expf(v.y - m), e2 = expf(v.z - m), e3 = expf(v.w - m);
  float s = e0 + e1 + e2 + e3;
#pragma unroll
  for (int off = 32; off > 0; off >>= 1) s += __shfl_xor(s, off, 64);
  const float inv = 1.0f / s;
  const float o0 = e0 * inv, o1 = e1 * inv, o2 = e2 * inv, o3 = e3 * inv;
  const int b = (int)(pix >> 14);
  const int h = (int)((pix >> 7) & 127);
  const int w = (int)(pix & 127);
  unsigned short* base = (unsigned short*)qkv_base + (size_t)b * kO * kL * 2;
  if (lane < 32) {
    unsigned short* dst = base + AROWT_OFF + (((size_t)h * kW + w) * 128 + lane * 4);
    *(uint2*)dst = make_uint2(pack_bf16x2(o0, o1), pack_bf16x2(o2, o3));
  } else {
    const int s32 = lane - 32;
    const int jb = s32 >> 3;
    const int lg = (s32 >> 1) & 3;
    const int eoff = (s32 & 1) * 4;
    const int hb = h >> 4, hr = h & 15;
    unsigned short* dst = base + (size_t)w * 16384
        + (((size_t)(jb * 8 + hb) * 64 + lg * 16 + hr) * 8 + eoff);
    *(uint2*)dst = make_uint2(pack_bf16x2(o0, o1), pack_bf16x2(o2, o3));
  }
}

// ---------------- vtrans: V fp32 -> vfrag bf16 (MFMA A-frag order) ----------------
__global__ __launch_bounds__(256) void vtrans_kernel(
    const float* __restrict__ qkv, unsigned short* __restrict__ vfrag) {
  __shared__ float sT[16 * VT_SW];   // 69,888 B : [w16][c16][j64]
  const int cb = blockIdx.x;         // 0..31
  const int wt = blockIdx.y;         // 0..7
  const int b  = blockIdx.z;
  const int t = threadIdx.x;
  const int lane = t & 63, wd = t >> 6;
  const int lr = lane & 15, lg = lane >> 4;
  const float* vb = qkv + ((size_t)b * kO + 128 + cb * 16) * kL + wt * 16;
  unsigned short* vfb = vfrag + (size_t)b * VFRAG_B;

  for (int half = 0; half < 2; ++half) {
    const int j0 = half * 64;
#pragma unroll
    for (int p = 0; p < 16; ++p) {
      const int g = p * 256 + t;
      const int wq = g & 3;
      const int j = (g >> 2) & 63;
      const int ci = p;
      float4 v = *(const float4*)(
          vb + (size_t)ci * kL + (size_t)(j0 + j) * kW + wq * 4);
      float* d = sT + ci * VT_SC + j;
      d[(wq * 4 + 0) * VT_SW] = v.x;
      d[(wq * 4 + 1) * VT_SW] = v.y;
      d[(wq * 4 + 2) * VT_SW] = v.z;
      d[(wq * 4 + 3) * VT_SW] = v.w;
    }
    __syncthreads();
#pragma unroll
    for (int wi = 0; wi < 4; ++wi) {
      const int w = wd * 4 + wi;
#pragma unroll
      for (int ktl = 0; ktl < 2; ++ktl) {
        const float* s = sT + w * VT_SW + lr * VT_SC + ktl * 32 + lg * 8;
        float a[8];
        *(float4*)(a + 0) = *(const float4*)(s + 0);
        *(float4*)(a + 4) = *(const float4*)(s + 4);
        const int ktg = half * 2 + ktl;
        unsigned short* dst = vfb
            + ((((size_t)(wt * 16 + w) * 32 + cb) * 4 + ktg) * 64 + lane) * 8;
        uint4 o = make_uint4(pack_bf16x2(a[0], a[1]), pack_bf16x2(a[2], a[3]),
                             pack_bf16x2(a[4], a[5]), pack_bf16x2(a[6], a[7]));
        *(uint4*)dst = o;
      }
    }
    __syncthreads();
  }
}

// ---------------- row aggregation via bf16 MFMA ----------------
__global__ __launch_bounds__(256) void rowagg_mfma(
    const float* qkv, float* __restrict__ out) {
  __shared__ short sV[128 * 64];
  const int ct = blockIdx.x;       // 0..3
  const int bh = blockIdx.y;
  const int b = bh >> 7, h = bh & 127;
  const int c0 = ct * 128;
  const int t = threadIdx.x;
  const int wid = t >> 6, lane = t & 63;
  const int wr = wid >> 1, wc = wid & 1;
  const int lr = lane & 15, lg = lane >> 4;

  f32x4 acc[4][4];
#pragma unroll
  for (int i = 0; i < 4; ++i)
#pragma unroll
    for (int j = 0; j < 4; ++j) acc[i][j] = (f32x4)(0.f);

  const float* vbase = qkv + ((size_t)b * kO + 128 + c0) * kL + (size_t)h * kW;
  const unsigned short* arbase = (const unsigned short*)qkv
      + (size_t)b * kO * kL * 2 + AROWT_OFF + (size_t)h * kW * 128;

  for (int kt = 0; kt < 2; ++kt) {
    const int i0 = kt * 64;
    {
      const int c = t >> 1;
      const int half = t & 1;
      const float* src = vbase + (size_t)c * kL + i0 + half * 32;
#pragma unroll
      for (int q = 0; q < 4; ++q) {
        const int g = half * 4 + q;
        float4 a0 = *(const float4*)(src + q * 8);
        float4 a1 = *(const float4*)(src + q * 8 + 4);
        unsigned* d = (unsigned*)&sV[c * 64 + ((g ^ (c & 7)) << 3)];
        d[0] = pack_bf16x2(a0.x, a0.y);
        d[1] = pack_bf16x2(a0.z, a0.w);
        d[2] = pack_bf16x2(a1.x, a1.y);
        d[3] = pack_bf16x2(a1.z, a1.w);
      }
    }
    __syncthreads();
#pragma unroll
    for (int ks = 0; ks < 2; ++ks) {
      bf16x8 vfr[4], afr[4];
#pragma unroll
      for (int mf = 0; mf < 4; ++mf) {
        const int row = wr * 64 + mf * 16 + lr;
        const int kg = ks * 4 + lg;
        vfr[mf] = *(const bf16x8*)&sV[row * 64 + ((kg ^ (row & 7)) << 3)];
      }
#pragma unroll
      for (int nf = 0; nf < 4; ++nf) {
        const int w = wc * 64 + nf * 16 + lr;
        afr[nf] = *(const bf16x8*)(arbase + (size_t)w * 128 + i0 + ks * 32 + lg * 8);
      }
#pragma unroll
      for (int mf = 0; mf < 4; ++mf)
#pragma unroll
        for (int nf = 0; nf < 4; ++nf)
          acc[mf][nf] = __builtin_amdgcn_mfma_f32_16x16x32_bf16(
              vfr[mf], afr[nf], acc[mf][nf], 0, 0, 0);
    }
    __syncthreads();
  }
#pragma unroll
  for (int mf = 0; mf < 4; ++mf) {
#pragma unroll
    for (int r = 0; r < 4; ++r) {
      const int c = c0 + wr * 64 + mf * 16 + lg * 4 + r;
      float* dst = out + (((size_t)b * kC + c) * kH + h) * kW + wc * 64;
#pragma unroll
      for (int nf = 0; nf < 4; ++nf) {
        dst[nf * 16 + lr] = acc[mf][nf][r];
      }
    }
  }
}

// ---------------- col aggregation: direct frag loads, h32 tiles, 4 blocks/CU ----
__global__ __launch_bounds__(1024) void colagg_mfma(
    const float* qkv, const unsigned short* __restrict__ vfrag,
    float* __restrict__ out) {
  __shared__ float sO[32 * SOC];      // 34,944 B (epilogue only) -> 4 blocks/CU
  const int gx = blockIdx.x;          // ct(8) + 8*ht(4)
  const int ct = gx & 7, ht = gx >> 3;
  const int c0 = ct * 64, h0 = ht * 32;
  const int w0 = blockIdx.y * 16;
  const int b = blockIdx.z;
  const int t = threadIdx.x;          // 0..1023
  const int wv = t >> 6, lane = t & 63;
  const int lr = lane & 15, lg = lane >> 4;
  const int w = w0 + wv;

  f32x4 acc[4][2];   // [mf(c)][nf(h: 2x16)]
#pragma unroll
  for (int i = 0; i < 4; ++i)
#pragma unroll
    for (int j = 0; j < 2; ++j) acc[i][j] = (f32x4)(0.f);

  const unsigned short* ab = (const unsigned short*)qkv + (size_t)b * kO * kL * 2
      + (size_t)w * 16384;
  const unsigned short* vfb = vfrag + (size_t)b * VFRAG_B
      + ((size_t)w * 32 + ct * 4) * 2048;

  for (int kt = 0; kt < 4; ++kt) {
    bf16x8 vf[4], af[2];
#pragma unroll
    for (int mf = 0; mf < 4; ++mf)
      vf[mf] = *(const bf16x8*)(vfb + ((size_t)mf * 2048 + kt * 512 + lane * 8));
#pragma unroll
    for (int nf = 0; nf < 2; ++nf)
      af[nf] = *(const bf16x8*)(
          ab + (((size_t)(kt * 8 + ht * 2 + nf) * 64 + lane) * 8));
#pragma unroll
    for (int mf = 0; mf < 4; ++mf)
#pragma unroll
      for (int nf = 0; nf < 2; ++nf)
        acc[mf][nf] = __builtin_amdgcn_mfma_f32_16x16x32_bf16(
            vf[mf], af[nf], acc[mf][nf], 0, 0, 0);
  }

  // ---- epilogue: per (nf, c-half): LDS transpose + coalesced RMW ----
  const int ew = t & 15, ehh = (t >> 4) & 15, ecb = t >> 8;
  for (int nf = 0; nf < 2; ++nf) {
#pragma unroll
    for (int chalf = 0; chalf < 2; ++chalf) {
      __syncthreads();
#pragma unroll
      for (int mi = 0; mi < 2; ++mi) {
        const int mf = chalf * 2 + mi;
#pragma unroll
        for (int r = 0; r < 4; ++r)
          sO[(mi * 16 + lg * 4 + r) * SOC + lr * SOW + wv] = acc[mf][nf][r];
      }
      __syncthreads();
#pragma unroll
      for (int q = 0; q < 8; ++q) {
        const int c = q * 4 + ecb;              // 0..31
        float* dst = out
            + (((size_t)b * kC + c0 + chalf * 32 + c) * kH + h0 + nf * 16 + ehh) * kW
            + w0 + ew;
        *dst += sO[c * SOC + ehh * SOW + ew];
      }
    }
  }
}

extern "C" void kernel_launch(void* const* d_in, const int* in_sizes, int n_in,
                              void* d_out, int out_size, void* d_ws, size_t ws_size,
                              hipStream_t stream) {
  (void)in_sizes; (void)n_in; (void)out_size; (void)ws_size;
  const float* x  = (const float*)d_in[0];
  const float* Wq = (const float*)d_in[1];
  const float* bq = (const float*)d_in[2];
  const float* Wk = (const float*)d_in[3];
  const float* bk = (const float*)d_in[4];
  const float* Wv = (const float*)d_in[5];
  const float* bv = (const float*)d_in[6];
  float* out = (float*)d_out;
  float* ws  = (float*)d_ws;

  short* wpk = (short*)(ws + OFF_WALL);
  float* ball = ws + OFF_BALL;
  float* qkv  = ws + OFF_QKV;
  float* e    = ws + OFF_E;
  short* xpk  = (short*)(ws + OFF_E);
  unsigned short* vfrag = (unsigned short*)(ws + OFF_E);

  pack_w<<<dim3(kO), dim3(256), 0, stream>>>(Wq, bq, Wk, bk, Wv, bv, wpk, ball);
  for (int b = 0; b < kB; ++b) {
    pack_x<<<dim3(kL / 64, kC / 64), dim3(256), 0, stream>>>(x, xpk, b);
    proj_mfma<<<dim3(5, kL / 128), dim3(256), 0, stream>>>(xpk, wpk, ball, qkv, b);
  }
  escore_mfma<0><<<dim3(kB * kH), dim3(256), 0, stream>>>(qkv, e);
  escore_mfma<1><<<dim3(kB * kW), dim3(256), 0, stream>>>(qkv, e);
  softmax_kernel<<<dim3(kB * kH * kW / 4), dim3(256), 0, stream>>>(e, qkv);
  vtrans_kernel<<<dim3(32, 8, kB), dim3(256), 0, stream>>>(qkv, vfrag);
  rowagg_mfma<<<dim3(4, kB * kH), dim3(256), 0, stream>>>(qkv, out);
  colagg_mfma<<<dim3(32, kW / 16, kB), dim3(1024), 0, stream>>>(qkv, vfrag, out);
}